// Round 17
// baseline (390.316 us; speedup 1.0000x reference)
//
#include <hip/hip_runtime.h>
#include <hip/hip_bf16.h>
#include <stdint.h>

#define R_ 32
#define H_ 256
#define GAMMA_ 10.0f

typedef __attribute__((ext_vector_type(4))) float f32x4;
typedef __attribute__((ext_vector_type(2))) float f32x2;
typedef __attribute__((ext_vector_type(8))) short bf16x8;

__device__ __forceinline__ unsigned short f2b(float f){
  union { float f; unsigned u; } v; v.f = f;
  unsigned r = v.u + 0x7FFFu + ((v.u >> 16) & 1u);
  return (unsigned short)(r >> 16);
}
__device__ __forceinline__ float b2f(unsigned short h){
  union { unsigned u; float f; } v; v.u = ((unsigned)h) << 16; return v.f;
}

#if __has_builtin(__builtin_amdgcn_cvt_pk_fp8_f32) && __has_builtin(__builtin_amdgcn_cvt_pk_f32_fp8)
#define HWFP8 1
#else
#define HWFP8 0
__device__ __forceinline__ unsigned f2fp8(float f){
  unsigned s = (__float_as_uint(f) >> 24) & 0x80u;
  float a = fminf(fabsf(f), 448.f);
  unsigned b = __float_as_uint(a);
  b += 0x7FFFFu + ((b >> 20) & 1u);
  unsigned code = (((b >> 23) - 120u) << 3) | ((b >> 20) & 7u);
  code = (a < 0.015625f) ? 0u : code;
  return (s | code) & 0xFFu;
}
__device__ __forceinline__ float fp82f(unsigned c){
  unsigned E = (c >> 3) & 15u, m = c & 7u, s = (c >> 7) & 1u;
  unsigned bits = ((E + 120u) << 23) | (m << 20) | (s << 31);
  float v = __uint_as_float(bits);
  return (E == 0) ? 0.f : v;
}
#endif

__device__ __forceinline__ unsigned pack4_fp8(float a0, float a1, float a2, float a3){
#if HWFP8
  unsigned pk = (unsigned)__builtin_amdgcn_cvt_pk_fp8_f32(a0, a1, 0, false);
  pk = (unsigned)__builtin_amdgcn_cvt_pk_fp8_f32(a2, a3, (int)pk, true);
  return pk;
#else
  return f2fp8(a0) | (f2fp8(a1) << 8) | (f2fp8(a2) << 16) | (f2fp8(a3) << 24);
#endif
}
__device__ __forceinline__ f32x4 unpack4_fp8(unsigned w){
#if HWFP8
  f32x2 lo = __builtin_amdgcn_cvt_pk_f32_fp8((int)w, false);
  f32x2 hi = __builtin_amdgcn_cvt_pk_f32_fp8((int)w, true);
  f32x4 r; r[0] = lo[0]; r[1] = lo[1]; r[2] = hi[0]; r[3] = hi[1];
  return r;
#else
  f32x4 r;
  r[0] = fp82f(w & 255u); r[1] = fp82f((w >> 8) & 255u);
  r[2] = fp82f((w >> 16) & 255u); r[3] = fp82f(w >> 24);
  return r;
#endif
}

// ================= prep mega-kernel: cvt | transw x3 | wqk x2 | rel | hist+flag =================
__global__ __launch_bounds__(256) void prep_kernel(
    const float* __restrict__ x, unsigned short* __restrict__ xb, int n4,
    const float* __restrict__ W1, unsigned short* __restrict__ Wt1,
    const float* __restrict__ W2, unsigned short* __restrict__ Wt2,
    const float* __restrict__ lin_w, unsigned short* __restrict__ linT,
    const float* __restrict__ q1, const float* __restrict__ k1, float* __restrict__ wqkT1,
    const float* __restrict__ q2, const float* __restrict__ k2, float* __restrict__ wqkT2,
    const float* __restrict__ rb, const float* __restrict__ rw,
    const float* __restrict__ rbias, float* __restrict__ relf,
    const int* __restrict__ srcp, const int* __restrict__ dst, const int* __restrict__ et,
    int* __restrict__ cnt2, int* __restrict__ flagA, int E, int Nn,
    int nb0, int nb_tw, int nb_lin, int nb_wqk, int nb_rel, int nb_hist){
  __shared__ float tile[32][33];
  const int bx = blockIdx.x, t = threadIdx.x;
  const int b0 = nb0, b1 = b0 + nb_tw, b2 = b1 + nb_tw, b3 = b2 + nb_lin;
  const int b4 = b3 + nb_wqk, b5 = b4 + nb_wqk, b6 = b5 + nb_rel;

  if (bx < b0){                                   // ---- cvt fp32->bf16
    int i = bx * 256 + t;
    if (i < n4){
      float4 v = ((const float4*)x)[i];
      ushort4 o; o.x=f2b(v.x); o.y=f2b(v.y); o.z=f2b(v.z); o.w=f2b(v.w);
      ((ushort4*)xb)[i] = o;
    }
    return;
  }
  if (bx < b3){                                   // ---- transw (W1 | W2 | lin)
    const float* W; unsigned short* Wt; int local;
    if (bx < b1){ W = W1; Wt = Wt1; local = bx - b0; }
    else if (bx < b2){ W = W2; Wt = Wt2; local = bx - b1; }
    else { W = lin_w; Wt = linT; local = bx - b2; }
    int i0 = (local & 7) * 32, o0 = ((local >> 3) & 7) * 32, r = local >> 6;
    int tx = t & 31, ty = t >> 5;
    const float* Wr = W + (size_t)r * 65536;
    for (int rr = ty; rr < 32; rr += 8)
      tile[rr][tx] = Wr[(size_t)(i0 + rr) * 256 + o0 + tx];
    __syncthreads();
    unsigned short* outr = Wt + (size_t)r * 65536;
    for (int rr = ty; rr < 32; rr += 8)
      outr[(size_t)(o0 + rr) * 256 + i0 + tx] = f2b(tile[tx][rr]);
    return;
  }
  if (bx < b5){                                   // ---- wqk (W1 | W2)
    bool first = bx < b4;
    int local = bx - (first ? b3 : b4);
    int w = t >> 6, lane = t & 63;
    int p = local * 4 + w;                        // 0..8191
    int i = p & 255, r = p >> 8;
    const float* W  = first ? W1 : W2;
    const float* qv = first ? q1 : q2;
    const float* kv = first ? k1 : k2;
    const float* row = W + ((size_t)r * 256 + i) * 256;
    float sq = 0.f, sk = 0.f;
    #pragma unroll
    for (int q4 = 0; q4 < 4; ++q4){
      int o = lane + q4 * 64;
      float wv = row[o];
      sq += wv * qv[r * 256 + o];
      sk += wv * kv[r * 256 + o];
    }
    #pragma unroll
    for (int o = 32; o; o >>= 1){ sq += __shfl_xor(sq, o); sk += __shfl_xor(sk, o); }
    if (!lane){
      float* wq = first ? wqkT1 : wqkT2;
      wq[i * 64 + r] = sq; wq[i * 64 + 32 + r] = sk;
    }
    return;
  }
  if (bx < b6){                                   // ---- rel embedding (fp32 for score)
    int r = bx - b5, h = t;
    float acc = rbias[h];
    const float* br = rb + (size_t)r * 768;
    for (int i = 0; i < 768; ++i) acc += br[i] * rw[(size_t)i * 256 + h];
    relf[r * 256 + h] = fmaxf(acc, 0.f);
    return;
  }
  {                                               // ---- hist (dst bins) + used-pair flag
    int e = (bx - b6) * 256 + t;
    if (e < E){
      int d = dst[e], r = et[e];
      atomicAdd(&cnt2[(d >> 5) * 1024 + (d & 31) * 32 + r], 1);
      flagA[r * Nn + srcp[e]] = 1;                // races write same value: fine
    }
  }
}

// ================= fused two-array scan chain =================
__global__ void totred_kernel(const int* __restrict__ cnt2, int* __restrict__ tot,
                              const int* __restrict__ flagA, int* __restrict__ tot2, int nblk1){
  __shared__ int red[256];
  int blk = blockIdx.x, t = threadIdx.x;
  const int* srcb = (blk < nblk1) ? (cnt2 + (size_t)blk * 1024) : (flagA + (size_t)(blk - nblk1) * 1024);
  int* dstb = (blk < nblk1) ? (tot + blk) : (tot2 + blk - nblk1);
  int s = 0;
  #pragma unroll
  for (int q = 0; q < 4; ++q) s += srcb[q * 256 + t];
  red[t] = s; __syncthreads();
  for (int o = 128; o; o >>= 1){ if (t < o) red[t] += red[t + o]; __syncthreads(); }
  if (!t) *dstb = red[0];
}
__device__ void scan_body(const int* deg, int* off, int n){
  __shared__ int carry;
  __shared__ int buf[1024];
  if (threadIdx.x == 0) carry = 0;
  __syncthreads();
  for (int base = 0; base < n; base += 1024){
    int i = base + threadIdx.x;
    int v = (i < n) ? deg[i] : 0;
    buf[threadIdx.x] = v; __syncthreads();
    for (int o = 1; o < 1024; o <<= 1){
      int t = (threadIdx.x >= o) ? buf[threadIdx.x - o] : 0;
      __syncthreads();
      buf[threadIdx.x] += t;
      __syncthreads();
    }
    if (i < n) off[i] = carry + buf[threadIdx.x] - v;   // exclusive
    __syncthreads();
    if (threadIdx.x == 1023) carry += buf[1023];
    __syncthreads();
  }
  if (threadIdx.x == 0) off[n] = carry;
  __syncthreads();
}
__global__ void scan_kernel(const int* __restrict__ d1, int* __restrict__ o1, int n1,
                            const int* __restrict__ d2, int* __restrict__ o2, int n2){
  scan_body(d1, o1, n1);
  scan_body(d2, o2, n2);
}
__global__ __launch_bounds__(256) void ps2scan_kernel(
    const int* __restrict__ cnt2, const int* __restrict__ base1, int* __restrict__ ps2, int nblk1,
    const int* __restrict__ flagA, const int* __restrict__ base2, int* __restrict__ ps3, int nblk2){
  __shared__ int sb[1024];
  int blk = blockIdx.x, t = threadIdx.x;
  const bool first = blk < nblk1;
  const int lb = first ? blk : blk - nblk1;
  const int* srcb = first ? (cnt2 + (size_t)lb * 1024) : (flagA + (size_t)lb * 1024);
  int* dstb = first ? (ps2 + (size_t)lb * 1024) : (ps3 + (size_t)lb * 1024);
  const int* base = first ? base1 : base2;
  int orig[4];
  #pragma unroll
  for (int q = 0; q < 4; ++q){ int i = q * 256 + t; orig[q] = srcb[i]; sb[i] = orig[q]; }
  __syncthreads();
  for (int o = 1; o < 1024; o <<= 1){
    int v[4];
    #pragma unroll
    for (int q = 0; q < 4; ++q){ int i = q * 256 + t; v[q] = (i >= o) ? sb[i - o] : 0; }
    __syncthreads();
    #pragma unroll
    for (int q = 0; q < 4; ++q){ int i = q * 256 + t; sb[i] += v[q]; }
    __syncthreads();
  }
  int b = base[lb];
  #pragma unroll
  for (int q = 0; q < 4; ++q){ int i = q * 256 + t; dstb[i] = b + sb[i] - orig[q]; }
  if (lb == 0 && t == 0){
    if (first) ps2[(size_t)nblk1 * 1024] = base1[nblk1];
    else       ps3[(size_t)nblk2 * 1024] = base2[nblk2];
  }
}
__global__ void nodelist_kernel(const int* __restrict__ flagA, const int* __restrict__ ps3,
                                int* __restrict__ nodelist, int ntot, int Nn){
  int i = blockIdx.x * 256 + threadIdx.x;
  if (i < ntot && flagA[i]) nodelist[ps3[i]] = i % Nn;
}
__global__ void scatter2_kernel(const int* __restrict__ src, const int* __restrict__ dst,
                                const int* __restrict__ et, const int* __restrict__ ps2,
                                const int* __restrict__ ps3, int* __restrict__ cur2,
                                int* __restrict__ es_src, int* __restrict__ es_row,
                                int* __restrict__ es_et, int* __restrict__ es_eid, int E, int Nn){
  int e = blockIdx.x * 256 + threadIdx.x;
  if (e >= E) return;
  int d = dst[e], r = et[e], s = src[e];
  int key = (d >> 5) * 1024 + (d & 31) * 32 + r;
  int pos = ps2[key] + atomicAdd(&cur2[key], 1);
  es_src[pos] = s;
  es_row[pos] = ps3[(size_t)r * Nn + s];          // compacted xt row for this edge
  es_et[pos]  = r;
  es_eid[pos] = e;
}

// ================= qdot standalone (4KB LDS, high occupancy) =================
__global__ void qdot_kernel(const unsigned short* __restrict__ xb, const float* __restrict__ wqkT,
                            float* __restrict__ qdot, float* __restrict__ kdot, int n){
  __shared__ float xrow[4][256];
  int w = threadIdx.x >> 6, lane = threadIdx.x & 63;
  int node = blockIdx.x * 4 + w;
  if (node >= n) return;
  ushort4 v = ((const ushort4*)(xb + (size_t)node * 256))[lane];
  float* xr = xrow[w];
  xr[lane * 4 + 0] = b2f(v.x);
  xr[lane * 4 + 1] = b2f(v.y);
  xr[lane * 4 + 2] = b2f(v.z);
  xr[lane * 4 + 3] = b2f(v.w);
  float acc = 0.f;
  #pragma unroll 8
  for (int kk = 0; kk < 256; ++kk)
    acc = fmaf(xr[kk], wqkT[kk * 64 + lane], acc);
  if (lane < 32) qdot[node * 32 + lane] = acc;
  else           kdot[node * 32 + lane - 32] = acc;
}

// ================= GEMM: BM=128 x BN=256; MODE0 -> fp8 packed-dword rows; MODE1 -> fp32+bias =================
template<int MODE>
__global__ __launch_bounds__(512) void gemm3_kernel(
    const unsigned short* __restrict__ A, const unsigned short* __restrict__ Bt,
    void* __restrict__ Cv, const float* __restrict__ bias, int M, int MT,
    const int* __restrict__ nodelist, const int* __restrict__ ps3, int Nn){
  __shared__ unsigned short As[2][128 * 64];
  __shared__ unsigned short Bs[2][256 * 64];
  __shared__ int rowsL[128];
  const int bx = blockIdx.x;
  const int r  = (MODE == 0) ? bx / MT : 0;
  const int mb = (MODE == 0) ? bx % MT : bx;
  int u0 = 0, u1 = M;
  if (MODE == 0){
    u0 = ps3[(size_t)r * Nn];
    u1 = ps3[(size_t)(r + 1) * Nn];
    if (mb * 128 >= u1 - u0) return;              // empty block for this relation
  }
  const int tid = threadIdx.x, lane = tid & 63, wid = tid >> 6;
  const int wm = (wid >> 2) * 64;
  const int wn = (wid & 3) * 64;
  const int lg = lane >> 4, lr = lane & 15;
  const unsigned short* Brel = Bt + (size_t)r * 65536;

  if (tid < 128){
    if (MODE == 0){
      int cr = u0 + mb * 128 + tid;
      if (cr >= u1) cr = u1 - 1;
      rowsL[tid] = nodelist[cr];
    } else {
      int g = mb * 128 + tid; if (g >= M) g = M - 1;
      rowsL[tid] = g;
    }
  }
  __syncthreads();

  f32x4 acc[4][4];
  #pragma unroll
  for (int i = 0; i < 4; ++i)
    #pragma unroll
    for (int j = 0; j < 4; ++j) acc[i][j] = (f32x4)0.0f;

  auto stage = [&](int buf, int kt){
    #pragma unroll
    for (int q = 0; q < 2; ++q){
      int ci = q * 512 + tid;
      int row = ci >> 3, p = ci & 7;
      int gch = p ^ (row & 7);                    // inverse-swizzled source
      const unsigned short* ga = A + (size_t)rowsL[row] * 256 + kt * 64 + gch * 8;
      __builtin_amdgcn_global_load_lds((const __attribute__((address_space(1))) void*)ga,
          (__attribute__((address_space(3))) void*)(As[buf] + (size_t)ci * 8), 16, 0, 0);
    }
    #pragma unroll
    for (int q = 0; q < 4; ++q){
      int ci = q * 512 + tid;
      int row = ci >> 3, p = ci & 7;
      int gch = p ^ (row & 7);
      const unsigned short* gb = Brel + (size_t)row * 256 + kt * 64 + gch * 8;
      __builtin_amdgcn_global_load_lds((const __attribute__((address_space(1))) void*)gb,
          (__attribute__((address_space(3))) void*)(Bs[buf] + (size_t)ci * 8), 16, 0, 0);
    }
  };

  stage(0, 0);
  __syncthreads();

  for (int kt = 0; kt < 4; ++kt){
    const int cur = kt & 1;
    if (kt < 3) stage(cur ^ 1, kt + 1);           // prefetch overlaps compute
    #pragma unroll
    for (int kk = 0; kk < 2; ++kk){
      bf16x8 af[4], bg[4];
      #pragma unroll
      for (int mi = 0; mi < 4; ++mi){
        int row = wm + mi * 16 + lr;
        int pc = (lg + kk * 4) ^ (row & 7);
        af[mi] = *(const bf16x8*)&As[cur][row * 64 + pc * 8];
      }
      #pragma unroll
      for (int ni = 0; ni < 4; ++ni){
        int row = wn + ni * 16 + lr;
        int pc = (lg + kk * 4) ^ (row & 7);
        bg[ni] = *(const bf16x8*)&Bs[cur][row * 64 + pc * 8];
      }
      #pragma unroll
      for (int mi = 0; mi < 4; ++mi)
        #pragma unroll
        for (int ni = 0; ni < 4; ++ni)
          acc[mi][ni] = __builtin_amdgcn_mfma_f32_16x16x32_bf16(af[mi], bg[ni], acc[mi][ni], 0, 0, 0);
    }
    __syncthreads();
  }

  // epilogue: C/D layout col=lane&15, row=(lane>>4)*4+reg
  if (MODE == 0){
    #pragma unroll
    for (int mi = 0; mi < 4; ++mi){
      #pragma unroll
      for (int j = 0; j < 4; ++j){
        int rowloc = wm + mi * 16 + lg * 4 + j;
        int cr = u0 + mb * 128 + rowloc;
        if (cr < u1){
          unsigned pk = pack4_fp8(acc[mi][0][j], acc[mi][1][j], acc[mi][2][j], acc[mi][3][j]);
          *(unsigned*)((unsigned char*)Cv + (size_t)cr * 256 + wn + lr * 4) = pk;
        }
      }
    }
  } else {
    #pragma unroll
    for (int mi = 0; mi < 4; ++mi){
      #pragma unroll
      for (int j = 0; j < 4; ++j){
        int rowm = mb * 128 + wm + mi * 16 + lg * 4 + j;
        if (rowm >= M) continue;
        #pragma unroll
        for (int ni = 0; ni < 4; ++ni){
          int col = wn + ni * 16 + lr;
          ((float*)Cv)[(size_t)rowm * H_ + col] = acc[mi][ni][j] + bias[col];
        }
      }
    }
  }
}

// ================= fused softmax + aggregation: wave per node (packed fp8 xt) =================
__global__ void attn_agg_kernel(const unsigned char* __restrict__ xt8, const float* __restrict__ qdot,
                                const float* __restrict__ kdot, const int* __restrict__ ps2,
                                const int* __restrict__ es_src, const int* __restrict__ es_row,
                                float* __restrict__ a, unsigned short* __restrict__ hout, int n){
  int w = threadIdx.x >> 6, lane = threadIdx.x & 63;
  int node = blockIdx.x * 4 + w;
  if (node >= n) return;
  int kb = (node >> 5) * 1024 + (node & 31) * 32;
  // ---- phase A: softmax stats; lane r owns the node's (et=r) run; store raw exp
  int s = 0, e = 0;
  float qd = 0.f;
  if (lane < 32){
    s = ps2[kb + lane]; e = ps2[kb + lane + 1];
    qd = qdot[node * 32 + lane];
  }
  float m = -1e30f;
  for (int j = s; j < e; ++j){
    float z = qd + kdot[es_src[j] * 32 + lane];
    z = (z > 0.f) ? z : 0.2f * z;          // leaky_relu 0.2
    a[j] = z;
    m = fmaxf(m, z);
  }
  #pragma unroll
  for (int o = 32; o; o >>= 1) m = fmaxf(m, __shfl_xor(m, o));
  float sum = 0.f;
  for (int j = s; j < e; ++j){
    float ez = __expf(a[j] - m);
    a[j] = ez; sum += ez;
  }
  #pragma unroll
  for (int o = 32; o; o >>= 1) sum += __shfl_xor(sum, o);
  float inv = 1.0f / (sum + 1e-16f);
  // ---- phase B: aggregate; lane L's dword (bytes 4L..4L+3) = cols (4L&192)+k*16+(L&15)
  int s0 = ps2[kb], s1 = ps2[kb + 32];
  float a0 = 0.f, a1 = 0.f, a2 = 0.f, a3 = 0.f;
  int j = s0;
  for (; j + 2 <= s1; j += 2){
    int r0 = es_row[j], r1 = es_row[j+1];
    float w0 = a[j], w1 = a[j+1];
    unsigned v0 = ((const unsigned*)(xt8 + (size_t)r0 * 256))[lane];
    unsigned v1 = ((const unsigned*)(xt8 + (size_t)r1 * 256))[lane];
    f32x4 d0 = unpack4_fp8(v0), d1 = unpack4_fp8(v1);
    a0 += w0*d0[0] + w1*d1[0];
    a1 += w0*d0[1] + w1*d1[1];
    a2 += w0*d0[2] + w1*d1[2];
    a3 += w0*d0[3] + w1*d1[3];
  }
  for (; j < s1; ++j){
    float wv = a[j];
    unsigned v = ((const unsigned*)(xt8 + (size_t)es_row[j] * 256))[lane];
    f32x4 d = unpack4_fp8(v);
    a0 = fmaf(wv, d[0], a0);
    a1 = fmaf(wv, d[1], a1);
    a2 = fmaf(wv, d[2], a2);
    a3 = fmaf(wv, d[3], a3);
  }
  // hout: actual col for byte k = (lane&48)*4 + k*16 + (lane&15)
  int cb = ((lane & 48) << 2) + (lane & 15);
  unsigned short* hn = hout + (size_t)node * H_;
  hn[cb +  0] = f2b(fmaxf(a0 * inv, 0.f));
  hn[cb + 16] = f2b(fmaxf(a1 * inv, 0.f));
  hn[cb + 32] = f2b(fmaxf(a2 * inv, 0.f));
  hn[cb + 48] = f2b(fmaxf(a3 * inv, 0.f));
}

// ================= TransE scoring: 16-lane groups, 4 edges in flight, fp32 h =================
__global__ void score3_kernel(const float* __restrict__ hb, const float* __restrict__ relf,
                              const int* __restrict__ ps2, const int* __restrict__ es_src,
                              const int* __restrict__ es_et, const int* __restrict__ es_eid,
                              float* __restrict__ out, int n){
  int w = threadIdx.x >> 6, lane = threadIdx.x & 63;
  int node = blockIdx.x * 4 + w;
  if (node >= n) return;
  const int g = lane >> 4, cl = lane & 15;        // group (edge slot), column-lane
  int kb = (node >> 5) * 1024 + (node & 31) * 32;
  int s0 = ps2[kb], s1 = ps2[kb + 32];
  // dst row: lane owns cols cl*16..cl*16+15 (4 x float4), resident in regs
  const float4* hd = (const float4*)(hb + (size_t)node * H_);
  float4 dv[4];
  #pragma unroll
  for (int q = 0; q < 4; ++q) dv[q] = hd[cl * 4 + q];

  auto edge_sum = [&](int j)->float{
    int sc = es_src[j], r = es_et[j];
    const float4* hs = (const float4*)(hb + (size_t)sc * H_);
    const float4* rv = (const float4*)(relf + (size_t)r * H_);
    float sum = 0.f;
    #pragma unroll
    for (int q = 0; q < 4; ++q){
      float4 a = hs[cl * 4 + q];
      float4 b = rv[cl * 4 + q];
      sum += fabsf(a.x + b.x - dv[q].x) + fabsf(a.y + b.y - dv[q].y)
           + fabsf(a.z + b.z - dv[q].z) + fabsf(a.w + b.w - dv[q].w);
    }
    return sum;
  };

  int j = s0 + g;
  for (; j + 4 < s1; j += 8){                     // 2 edges per group in flight
    float sA = edge_sum(j), sB = edge_sum(j + 4);
    #pragma unroll
    for (int o = 8; o; o >>= 1){ sA += __shfl_xor(sA, o); sB += __shfl_xor(sB, o); }
    if (!cl){ out[es_eid[j]] = GAMMA_ - sA; out[es_eid[j + 4]] = GAMMA_ - sB; }
  }
  if (j < s1){
    float sA = edge_sum(j);
    #pragma unroll
    for (int o = 8; o; o >>= 1) sA += __shfl_xor(sA, o);
    if (!cl) out[es_eid[j]] = GAMMA_ - sA;
  }
}

extern "C" void kernel_launch(void* const* d_in, const int* in_sizes, int n_in,
                              void* d_out, int out_size, void* d_ws, size_t ws_size,
                              hipStream_t stream){
  const float* x         = (const float*)d_in[0];
  const int*   edge_idx  = (const int*)d_in[1];
  const int*   edge_type = (const int*)d_in[2];
  const float* W1        = (const float*)d_in[3];
  const float* q1        = (const float*)d_in[4];
  const float* k1        = (const float*)d_in[5];
  const float* W2        = (const float*)d_in[6];
  const float* q2        = (const float*)d_in[7];
  const float* k2        = (const float*)d_in[8];
  const float* lin_w     = (const float*)d_in[9];
  const float* lin_b     = (const float*)d_in[10];
  const float* rel_bert  = (const float*)d_in[11];
  const float* rel_lin_w = (const float*)d_in[12];
  const float* rel_lin_b = (const float*)d_in[13];
  float* score = (float*)d_out;

  const int Nn = in_sizes[0] / H_;   // 10000
  const int E  = in_sizes[1] / 2;    // 320000
  const int* src_a = edge_idx;
  const int* dst_a = edge_idx + E;
  const int NBLK   = (Nn + 31) / 32;              // 313 dst-bin blocks
  const int NBINS  = NBLK * 1024;
  const int NB2    = (R_ * Nn + 1023) / 1024;     // 313 flag blocks
  const int NBINS2 = NB2 * 1024;

  // workspace carve-up (256B aligned)
  char* ws = (char*)d_ws;
  size_t cur_off = 0;
  auto carve = [&](size_t bytes)->char*{
    char* p = ws + cur_off;
    cur_off += (bytes + 255) & ~(size_t)255;
    return p;
  };
  unsigned char*  xt8  = (unsigned char*)carve((size_t)Nn * R_ * H_);      // fp8, worst case
  unsigned short* xb   = (unsigned short*)carve((size_t)Nn * H_ * 2);
  unsigned short* h1   = (unsigned short*)carve((size_t)Nn * H_ * 2);
  unsigned short* h2   = (unsigned short*)carve((size_t)Nn * H_ * 2);
  float*          outb = (float*)carve((size_t)Nn * H_ * 4);
  unsigned short* Wt1  = (unsigned short*)carve((size_t)R_ * 65536 * 2);
  unsigned short* Wt2  = (unsigned short*)carve((size_t)R_ * 65536 * 2);
  unsigned short* linT = (unsigned short*)carve(65536 * 2);
  float* relf  = (float*)carve((size_t)R_ * H_ * 4);
  float* wqkT1 = (float*)carve(64 * H_ * 4);
  float* wqkT2 = (float*)carve(64 * H_ * 4);
  float* qdot  = (float*)carve((size_t)Nn * R_ * 4);
  float* kdot  = (float*)carve((size_t)Nn * R_ * 4);
  int* cnt2    = (int*)carve((size_t)NBINS * 4);
  int* cur2    = (int*)carve((size_t)NBINS * 4);
  int* flagA   = (int*)carve((size_t)NBINS2 * 4);
  int* tot     = (int*)carve((size_t)NBLK * 4);
  int* tot2    = (int*)carve((size_t)NB2 * 4);
  int* baseA   = (int*)carve((size_t)(NBLK + 1) * 4);
  int* base2   = (int*)carve((size_t)(NB2 + 1) * 4);
  int* ps2     = (int*)carve((size_t)(NBINS + 1) * 4);
  int* ps3     = (int*)carve((size_t)(NBINS2 + 1) * 4);
  int* nodelist= (int*)carve((size_t)(R_ * Nn) * 4);
  int* es_src  = (int*)carve((size_t)E * 4);
  int* es_row  = (int*)carve((size_t)E * 4);
  int* es_et   = (int*)carve((size_t)E * 4);
  int* es_eid  = (int*)carve((size_t)E * 4);
  float* attn  = (float*)carve((size_t)E * 4);
  (void)ws_size; (void)n_in; (void)out_size;

  const int mt = (Nn + 127) / 128;         // 79
  const int nqd = (Nn + 3) / 4;            // 2500

  // prep block ranges
  const int n4 = Nn * H_ / 4;
  const int nb0 = (n4 + 255) / 256, nb_tw = 2048, nb_lin = 64, nb_wqk = 2048, nb_rel = 32;
  const int nb_hist = (E + 255) / 256;
  const int nprep = nb0 + 2 * nb_tw + nb_lin + 2 * nb_wqk + nb_rel + nb_hist;

  hipMemsetAsync(cnt2, 0, (size_t)NBINS * 4, stream);
  hipMemsetAsync(cur2, 0, (size_t)NBINS * 4, stream);
  hipMemsetAsync(flagA, 0, (size_t)NBINS2 * 4, stream);

  prep_kernel<<<nprep, 256, 0, stream>>>(
      x, xb, n4, W1, Wt1, W2, Wt2, lin_w, linT,
      q1, k1, wqkT1, q2, k2, wqkT2,
      rel_bert, rel_lin_w, rel_lin_b, relf,
      src_a, dst_a, edge_type, cnt2, flagA, E, Nn,
      nb0, nb_tw, nb_lin, nb_wqk, nb_rel, nb_hist);

  totred_kernel<<<NBLK + NB2, 256, 0, stream>>>(cnt2, tot, flagA, tot2, NBLK);
  scan_kernel<<<1, 1024, 0, stream>>>(tot, baseA, NBLK, tot2, base2, NB2);
  ps2scan_kernel<<<NBLK + NB2, 256, 0, stream>>>(cnt2, baseA, ps2, NBLK, flagA, base2, ps3, NB2);
  nodelist_kernel<<<(NBINS2 + 255) / 256, 256, 0, stream>>>(flagA, ps3, nodelist, R_ * Nn, Nn);
  scatter2_kernel<<<(E + 255) / 256, 256, 0, stream>>>(src_a, dst_a, edge_type, ps2, ps3, cur2,
                                                       es_src, es_row, es_et, es_eid, E, Nn);

  // ---- layer 1 ----
  gemm3_kernel<0><<<R_ * mt, 512, 0, stream>>>(xb, Wt1, xt8, nullptr, Nn, mt, nodelist, ps3, Nn);
  qdot_kernel<<<nqd, 256, 0, stream>>>(xb, wqkT1, qdot, kdot, Nn);
  attn_agg_kernel<<<nqd, 256, 0, stream>>>(xt8, qdot, kdot, ps2, es_src, es_row, attn, h1, Nn);

  // ---- layer 2 ----
  gemm3_kernel<0><<<R_ * mt, 512, 0, stream>>>(h1, Wt2, xt8, nullptr, Nn, mt, nodelist, ps3, Nn);
  qdot_kernel<<<nqd, 256, 0, stream>>>(h1, wqkT2, qdot, kdot, Nn);
  attn_agg_kernel<<<nqd, 256, 0, stream>>>(xt8, qdot, kdot, ps2, es_src, es_row, attn, h2, Nn);

  // ---- final linear + scoring ----
  gemm3_kernel<1><<<mt, 512, 0, stream>>>(h2, linT, outb, lin_b, Nn, mt, nullptr, nullptr, Nn);
  score3_kernel<<<nqd, 256, 0, stream>>>(outb, relf, ps2, es_src, es_et, es_eid, score, Nn);
}

// Round 18
// 368.703 us; speedup vs baseline: 1.0586x; 1.0586x over previous
//
#include <hip/hip_runtime.h>
#include <hip/hip_bf16.h>
#include <stdint.h>

#define R_ 32
#define H_ 256
#define GAMMA_ 10.0f

typedef __attribute__((ext_vector_type(4))) float f32x4;
typedef __attribute__((ext_vector_type(2))) float f32x2;
typedef __attribute__((ext_vector_type(8))) short bf16x8;

__device__ __forceinline__ unsigned short f2b(float f){
  union { float f; unsigned u; } v; v.f = f;
  unsigned r = v.u + 0x7FFFu + ((v.u >> 16) & 1u);
  return (unsigned short)(r >> 16);
}
__device__ __forceinline__ float b2f(unsigned short h){
  union { unsigned u; float f; } v; v.u = ((unsigned)h) << 16; return v.f;
}

#if __has_builtin(__builtin_amdgcn_cvt_pk_fp8_f32) && __has_builtin(__builtin_amdgcn_cvt_pk_f32_fp8)
#define HWFP8 1
#else
#define HWFP8 0
__device__ __forceinline__ unsigned f2fp8(float f){
  unsigned s = (__float_as_uint(f) >> 24) & 0x80u;
  float a = fminf(fabsf(f), 448.f);
  unsigned b = __float_as_uint(a);
  b += 0x7FFFFu + ((b >> 20) & 1u);
  unsigned code = (((b >> 23) - 120u) << 3) | ((b >> 20) & 7u);
  code = (a < 0.015625f) ? 0u : code;
  return (s | code) & 0xFFu;
}
__device__ __forceinline__ float fp82f(unsigned c){
  unsigned E = (c >> 3) & 15u, m = c & 7u, s = (c >> 7) & 1u;
  unsigned bits = ((E + 120u) << 23) | (m << 20) | (s << 31);
  float v = __uint_as_float(bits);
  return (E == 0) ? 0.f : v;
}
#endif

__device__ __forceinline__ unsigned pack4_fp8(float a0, float a1, float a2, float a3){
#if HWFP8
  unsigned pk = (unsigned)__builtin_amdgcn_cvt_pk_fp8_f32(a0, a1, 0, false);
  pk = (unsigned)__builtin_amdgcn_cvt_pk_fp8_f32(a2, a3, (int)pk, true);
  return pk;
#else
  return f2fp8(a0) | (f2fp8(a1) << 8) | (f2fp8(a2) << 16) | (f2fp8(a3) << 24);
#endif
}
__device__ __forceinline__ f32x4 unpack4_fp8(unsigned w){
#if HWFP8
  f32x2 lo = __builtin_amdgcn_cvt_pk_f32_fp8((int)w, false);
  f32x2 hi = __builtin_amdgcn_cvt_pk_f32_fp8((int)w, true);
  f32x4 r; r[0] = lo[0]; r[1] = lo[1]; r[2] = hi[0]; r[3] = hi[1];
  return r;
#else
  f32x4 r;
  r[0] = fp82f(w & 255u); r[1] = fp82f((w >> 8) & 255u);
  r[2] = fp82f((w >> 16) & 255u); r[3] = fp82f(w >> 24);
  return r;
#endif
}

// ================= prep mega-kernel: cvt | transw x3 | wqk x2 | rel | hist+flag =================
__global__ __launch_bounds__(256) void prep_kernel(
    const float* __restrict__ x, unsigned short* __restrict__ xb, int n4,
    const float* __restrict__ W1, unsigned short* __restrict__ Wt1,
    const float* __restrict__ W2, unsigned short* __restrict__ Wt2,
    const float* __restrict__ lin_w, unsigned short* __restrict__ linT,
    const float* __restrict__ q1, const float* __restrict__ k1, float* __restrict__ wqkT1,
    const float* __restrict__ q2, const float* __restrict__ k2, float* __restrict__ wqkT2,
    const float* __restrict__ rb, const float* __restrict__ rw,
    const float* __restrict__ rbias, float* __restrict__ relf,
    const int* __restrict__ srcp, const int* __restrict__ dst, const int* __restrict__ et,
    int* __restrict__ cnt2, int* __restrict__ flagA, int E, int Nn,
    int nb0, int nb_tw, int nb_lin, int nb_wqk, int nb_rel, int nb_hist){
  __shared__ float tile[32][33];
  const int bx = blockIdx.x, t = threadIdx.x;
  const int b0 = nb0, b1 = b0 + nb_tw, b2 = b1 + nb_tw, b3 = b2 + nb_lin;
  const int b4 = b3 + nb_wqk, b5 = b4 + nb_wqk, b6 = b5 + nb_rel;

  if (bx < b0){                                   // ---- cvt fp32->bf16
    int i = bx * 256 + t;
    if (i < n4){
      float4 v = ((const float4*)x)[i];
      ushort4 o; o.x=f2b(v.x); o.y=f2b(v.y); o.z=f2b(v.z); o.w=f2b(v.w);
      ((ushort4*)xb)[i] = o;
    }
    return;
  }
  if (bx < b3){                                   // ---- transw (W1 | W2 | lin)
    const float* W; unsigned short* Wt; int local;
    if (bx < b1){ W = W1; Wt = Wt1; local = bx - b0; }
    else if (bx < b2){ W = W2; Wt = Wt2; local = bx - b1; }
    else { W = lin_w; Wt = linT; local = bx - b2; }
    int i0 = (local & 7) * 32, o0 = ((local >> 3) & 7) * 32, r = local >> 6;
    int tx = t & 31, ty = t >> 5;
    const float* Wr = W + (size_t)r * 65536;
    for (int rr = ty; rr < 32; rr += 8)
      tile[rr][tx] = Wr[(size_t)(i0 + rr) * 256 + o0 + tx];
    __syncthreads();
    unsigned short* outr = Wt + (size_t)r * 65536;
    for (int rr = ty; rr < 32; rr += 8)
      outr[(size_t)(o0 + rr) * 256 + i0 + tx] = f2b(tile[tx][rr]);
    return;
  }
  if (bx < b5){                                   // ---- wqk (W1 | W2)
    bool first = bx < b4;
    int local = bx - (first ? b3 : b4);
    int w = t >> 6, lane = t & 63;
    int p = local * 4 + w;                        // 0..8191
    int i = p & 255, r = p >> 8;
    const float* W  = first ? W1 : W2;
    const float* qv = first ? q1 : q2;
    const float* kv = first ? k1 : k2;
    const float* row = W + ((size_t)r * 256 + i) * 256;
    float sq = 0.f, sk = 0.f;
    #pragma unroll
    for (int q4 = 0; q4 < 4; ++q4){
      int o = lane + q4 * 64;
      float wv = row[o];
      sq += wv * qv[r * 256 + o];
      sk += wv * kv[r * 256 + o];
    }
    #pragma unroll
    for (int o = 32; o; o >>= 1){ sq += __shfl_xor(sq, o); sk += __shfl_xor(sk, o); }
    if (!lane){
      float* wq = first ? wqkT1 : wqkT2;
      wq[i * 64 + r] = sq; wq[i * 64 + 32 + r] = sk;
    }
    return;
  }
  if (bx < b6){                                   // ---- rel embedding (fp32 for score)
    int r = bx - b5, h = t;
    float acc = rbias[h];
    const float* br = rb + (size_t)r * 768;
    for (int i = 0; i < 768; ++i) acc += br[i] * rw[(size_t)i * 256 + h];
    relf[r * 256 + h] = fmaxf(acc, 0.f);
    return;
  }
  {                                               // ---- hist (dst bins) + used-pair flag
    int e = (bx - b6) * 256 + t;
    if (e < E){
      int d = dst[e], r = et[e];
      atomicAdd(&cnt2[(d >> 5) * 1024 + (d & 31) * 32 + r], 1);
      flagA[r * Nn + srcp[e]] = 1;                // races write same value: fine
    }
  }
}

// ================= fused two-array scan chain =================
__global__ void totred_kernel(const int* __restrict__ cnt2, int* __restrict__ tot,
                              const int* __restrict__ flagA, int* __restrict__ tot2, int nblk1){
  __shared__ int red[256];
  int blk = blockIdx.x, t = threadIdx.x;
  const int* srcb = (blk < nblk1) ? (cnt2 + (size_t)blk * 1024) : (flagA + (size_t)(blk - nblk1) * 1024);
  int* dstb = (blk < nblk1) ? (tot + blk) : (tot2 + blk - nblk1);
  int s = 0;
  #pragma unroll
  for (int q = 0; q < 4; ++q) s += srcb[q * 256 + t];
  red[t] = s; __syncthreads();
  for (int o = 128; o; o >>= 1){ if (t < o) red[t] += red[t + o]; __syncthreads(); }
  if (!t) *dstb = red[0];
}
__device__ void scan_body(const int* deg, int* off, int n){
  __shared__ int carry;
  __shared__ int buf[1024];
  if (threadIdx.x == 0) carry = 0;
  __syncthreads();
  for (int base = 0; base < n; base += 1024){
    int i = base + threadIdx.x;
    int v = (i < n) ? deg[i] : 0;
    buf[threadIdx.x] = v; __syncthreads();
    for (int o = 1; o < 1024; o <<= 1){
      int t = (threadIdx.x >= o) ? buf[threadIdx.x - o] : 0;
      __syncthreads();
      buf[threadIdx.x] += t;
      __syncthreads();
    }
    if (i < n) off[i] = carry + buf[threadIdx.x] - v;   // exclusive
    __syncthreads();
    if (threadIdx.x == 1023) carry += buf[1023];
    __syncthreads();
  }
  if (threadIdx.x == 0) off[n] = carry;
  __syncthreads();
}
__global__ void scan_kernel(const int* __restrict__ d1, int* __restrict__ o1, int n1,
                            const int* __restrict__ d2, int* __restrict__ o2, int n2){
  scan_body(d1, o1, n1);
  scan_body(d2, o2, n2);
}
__global__ __launch_bounds__(256) void ps2scan_kernel(
    const int* __restrict__ cnt2, const int* __restrict__ base1, int* __restrict__ ps2, int nblk1,
    const int* __restrict__ flagA, const int* __restrict__ base2, int* __restrict__ ps3, int nblk2){
  __shared__ int sb[1024];
  int blk = blockIdx.x, t = threadIdx.x;
  const bool first = blk < nblk1;
  const int lb = first ? blk : blk - nblk1;
  const int* srcb = first ? (cnt2 + (size_t)lb * 1024) : (flagA + (size_t)lb * 1024);
  int* dstb = first ? (ps2 + (size_t)lb * 1024) : (ps3 + (size_t)lb * 1024);
  const int* base = first ? base1 : base2;
  int orig[4];
  #pragma unroll
  for (int q = 0; q < 4; ++q){ int i = q * 256 + t; orig[q] = srcb[i]; sb[i] = orig[q]; }
  __syncthreads();
  for (int o = 1; o < 1024; o <<= 1){
    int v[4];
    #pragma unroll
    for (int q = 0; q < 4; ++q){ int i = q * 256 + t; v[q] = (i >= o) ? sb[i - o] : 0; }
    __syncthreads();
    #pragma unroll
    for (int q = 0; q < 4; ++q){ int i = q * 256 + t; sb[i] += v[q]; }
    __syncthreads();
  }
  int b = base[lb];
  #pragma unroll
  for (int q = 0; q < 4; ++q){ int i = q * 256 + t; dstb[i] = b + sb[i] - orig[q]; }
  if (lb == 0 && t == 0){
    if (first) ps2[(size_t)nblk1 * 1024] = base1[nblk1];
    else       ps3[(size_t)nblk2 * 1024] = base2[nblk2];
  }
}
__global__ void nodelist_kernel(const int* __restrict__ flagA, const int* __restrict__ ps3,
                                int* __restrict__ nodelist, int ntot, int Nn){
  int i = blockIdx.x * 256 + threadIdx.x;
  if (i < ntot && flagA[i]) nodelist[ps3[i]] = i % Nn;
}
__global__ void scatter2_kernel(const int* __restrict__ src, const int* __restrict__ dst,
                                const int* __restrict__ et, const int* __restrict__ ps2,
                                const int* __restrict__ ps3, int* __restrict__ cur2,
                                int* __restrict__ es_src, int* __restrict__ es_row,
                                int* __restrict__ es_et, int* __restrict__ es_eid, int E, int Nn){
  int e = blockIdx.x * 256 + threadIdx.x;
  if (e >= E) return;
  int d = dst[e], r = et[e], s = src[e];
  int key = (d >> 5) * 1024 + (d & 31) * 32 + r;
  int pos = ps2[key] + atomicAdd(&cur2[key], 1);
  es_src[pos] = s;
  es_row[pos] = ps3[(size_t)r * Nn + s];          // compacted xt row for this edge
  es_et[pos]  = r;
  es_eid[pos] = e;
}

// ================= qdot standalone (4KB LDS, high occupancy) =================
__global__ void qdot_kernel(const unsigned short* __restrict__ xb, const float* __restrict__ wqkT,
                            float* __restrict__ qdot, float* __restrict__ kdot, int n){
  __shared__ float xrow[4][256];
  int w = threadIdx.x >> 6, lane = threadIdx.x & 63;
  int node = blockIdx.x * 4 + w;
  if (node >= n) return;
  ushort4 v = ((const ushort4*)(xb + (size_t)node * 256))[lane];
  float* xr = xrow[w];
  xr[lane * 4 + 0] = b2f(v.x);
  xr[lane * 4 + 1] = b2f(v.y);
  xr[lane * 4 + 2] = b2f(v.z);
  xr[lane * 4 + 3] = b2f(v.w);
  float acc = 0.f;
  #pragma unroll 8
  for (int kk = 0; kk < 256; ++kk)
    acc = fmaf(xr[kk], wqkT[kk * 64 + lane], acc);
  if (lane < 32) qdot[node * 32 + lane] = acc;
  else           kdot[node * 32 + lane - 32] = acc;
}

// ================= GEMM: BM=128 x BN=256; MODE0 -> fp8 packed-dword rows; MODE1 -> bf16+bias =================
template<int MODE>
__global__ __launch_bounds__(512) void gemm3_kernel(
    const unsigned short* __restrict__ A, const unsigned short* __restrict__ Bt,
    void* __restrict__ Cv, const float* __restrict__ bias, int M, int MT,
    const int* __restrict__ nodelist, const int* __restrict__ ps3, int Nn){
  __shared__ unsigned short As[2][128 * 64];
  __shared__ unsigned short Bs[2][256 * 64];
  __shared__ int rowsL[128];
  const int bx = blockIdx.x;
  const int r  = (MODE == 0) ? bx / MT : 0;
  const int mb = (MODE == 0) ? bx % MT : bx;
  int u0 = 0, u1 = M;
  if (MODE == 0){
    u0 = ps3[(size_t)r * Nn];
    u1 = ps3[(size_t)(r + 1) * Nn];
    if (mb * 128 >= u1 - u0) return;              // empty block for this relation
  }
  const int tid = threadIdx.x, lane = tid & 63, wid = tid >> 6;
  const int wm = (wid >> 2) * 64;
  const int wn = (wid & 3) * 64;
  const int lg = lane >> 4, lr = lane & 15;
  const unsigned short* Brel = Bt + (size_t)r * 65536;

  if (tid < 128){
    if (MODE == 0){
      int cr = u0 + mb * 128 + tid;
      if (cr >= u1) cr = u1 - 1;
      rowsL[tid] = nodelist[cr];
    } else {
      int g = mb * 128 + tid; if (g >= M) g = M - 1;
      rowsL[tid] = g;
    }
  }
  __syncthreads();

  f32x4 acc[4][4];
  #pragma unroll
  for (int i = 0; i < 4; ++i)
    #pragma unroll
    for (int j = 0; j < 4; ++j) acc[i][j] = (f32x4)0.0f;

  auto stage = [&](int buf, int kt){
    #pragma unroll
    for (int q = 0; q < 2; ++q){
      int ci = q * 512 + tid;
      int row = ci >> 3, p = ci & 7;
      int gch = p ^ (row & 7);                    // inverse-swizzled source
      const unsigned short* ga = A + (size_t)rowsL[row] * 256 + kt * 64 + gch * 8;
      __builtin_amdgcn_global_load_lds((const __attribute__((address_space(1))) void*)ga,
          (__attribute__((address_space(3))) void*)(As[buf] + (size_t)ci * 8), 16, 0, 0);
    }
    #pragma unroll
    for (int q = 0; q < 4; ++q){
      int ci = q * 512 + tid;
      int row = ci >> 3, p = ci & 7;
      int gch = p ^ (row & 7);
      const unsigned short* gb = Brel + (size_t)row * 256 + kt * 64 + gch * 8;
      __builtin_amdgcn_global_load_lds((const __attribute__((address_space(1))) void*)gb,
          (__attribute__((address_space(3))) void*)(Bs[buf] + (size_t)ci * 8), 16, 0, 0);
    }
  };

  stage(0, 0);
  __syncthreads();

  for (int kt = 0; kt < 4; ++kt){
    const int cur = kt & 1;
    if (kt < 3) stage(cur ^ 1, kt + 1);           // prefetch overlaps compute
    #pragma unroll
    for (int kk = 0; kk < 2; ++kk){
      bf16x8 af[4], bg[4];
      #pragma unroll
      for (int mi = 0; mi < 4; ++mi){
        int row = wm + mi * 16 + lr;
        int pc = (lg + kk * 4) ^ (row & 7);
        af[mi] = *(const bf16x8*)&As[cur][row * 64 + pc * 8];
      }
      #pragma unroll
      for (int ni = 0; ni < 4; ++ni){
        int row = wn + ni * 16 + lr;
        int pc = (lg + kk * 4) ^ (row & 7);
        bg[ni] = *(const bf16x8*)&Bs[cur][row * 64 + pc * 8];
      }
      #pragma unroll
      for (int mi = 0; mi < 4; ++mi)
        #pragma unroll
        for (int ni = 0; ni < 4; ++ni)
          acc[mi][ni] = __builtin_amdgcn_mfma_f32_16x16x32_bf16(af[mi], bg[ni], acc[mi][ni], 0, 0, 0);
    }
    __syncthreads();
  }

  // epilogue: C/D layout col=lane&15, row=(lane>>4)*4+reg
  if (MODE == 0){
    #pragma unroll
    for (int mi = 0; mi < 4; ++mi){
      #pragma unroll
      for (int j = 0; j < 4; ++j){
        int rowloc = wm + mi * 16 + lg * 4 + j;
        int cr = u0 + mb * 128 + rowloc;
        if (cr < u1){
          unsigned pk = pack4_fp8(acc[mi][0][j], acc[mi][1][j], acc[mi][2][j], acc[mi][3][j]);
          *(unsigned*)((unsigned char*)Cv + (size_t)cr * 256 + wn + lr * 4) = pk;
        }
      }
    }
  } else {
    #pragma unroll
    for (int mi = 0; mi < 4; ++mi){
      #pragma unroll
      for (int j = 0; j < 4; ++j){
        int rowm = mb * 128 + wm + mi * 16 + lg * 4 + j;
        if (rowm >= M) continue;
        #pragma unroll
        for (int ni = 0; ni < 4; ++ni){
          int col = wn + ni * 16 + lr;
          ((unsigned short*)Cv)[(size_t)rowm * H_ + col] = f2b(acc[mi][ni][j] + bias[col]);
        }
      }
    }
  }
}

// ================= fused softmax + aggregation: wave per node (packed fp8 xt) =================
__global__ void attn_agg_kernel(const unsigned char* __restrict__ xt8, const float* __restrict__ qdot,
                                const float* __restrict__ kdot, const int* __restrict__ ps2,
                                const int* __restrict__ es_src, const int* __restrict__ es_row,
                                float* __restrict__ a, unsigned short* __restrict__ hout, int n){
  int w = threadIdx.x >> 6, lane = threadIdx.x & 63;
  int node = blockIdx.x * 4 + w;
  if (node >= n) return;
  int kb = (node >> 5) * 1024 + (node & 31) * 32;
  // ---- phase A: softmax stats; lane r owns the node's (et=r) run; store raw exp
  int s = 0, e = 0;
  float qd = 0.f;
  if (lane < 32){
    s = ps2[kb + lane]; e = ps2[kb + lane + 1];
    qd = qdot[node * 32 + lane];
  }
  float m = -1e30f;
  for (int j = s; j < e; ++j){
    float z = qd + kdot[es_src[j] * 32 + lane];
    z = (z > 0.f) ? z : 0.2f * z;          // leaky_relu 0.2
    a[j] = z;
    m = fmaxf(m, z);
  }
  #pragma unroll
  for (int o = 32; o; o >>= 1) m = fmaxf(m, __shfl_xor(m, o));
  float sum = 0.f;
  for (int j = s; j < e; ++j){
    float ez = __expf(a[j] - m);
    a[j] = ez; sum += ez;
  }
  #pragma unroll
  for (int o = 32; o; o >>= 1) sum += __shfl_xor(sum, o);
  float inv = 1.0f / (sum + 1e-16f);
  // ---- phase B: aggregate; lane L's dword (bytes 4L..4L+3) = cols (4L&192)+k*16+(L&15)
  int s0 = ps2[kb], s1 = ps2[kb + 32];
  float a0 = 0.f, a1 = 0.f, a2 = 0.f, a3 = 0.f;
  int j = s0;
  for (; j + 2 <= s1; j += 2){
    int r0 = es_row[j], r1 = es_row[j+1];
    float w0 = a[j], w1 = a[j+1];
    unsigned v0 = ((const unsigned*)(xt8 + (size_t)r0 * 256))[lane];
    unsigned v1 = ((const unsigned*)(xt8 + (size_t)r1 * 256))[lane];
    f32x4 d0 = unpack4_fp8(v0), d1 = unpack4_fp8(v1);
    a0 += w0*d0[0] + w1*d1[0];
    a1 += w0*d0[1] + w1*d1[1];
    a2 += w0*d0[2] + w1*d1[2];
    a3 += w0*d0[3] + w1*d1[3];
  }
  for (; j < s1; ++j){
    float wv = a[j];
    unsigned v = ((const unsigned*)(xt8 + (size_t)es_row[j] * 256))[lane];
    f32x4 d = unpack4_fp8(v);
    a0 = fmaf(wv, d[0], a0);
    a1 = fmaf(wv, d[1], a1);
    a2 = fmaf(wv, d[2], a2);
    a3 = fmaf(wv, d[3], a3);
  }
  // hout: actual col for byte k = (lane&48)*4 + k*16 + (lane&15)
  int cb = ((lane & 48) << 2) + (lane & 15);
  unsigned short* hn = hout + (size_t)node * H_;
  hn[cb +  0] = f2b(fmaxf(a0 * inv, 0.f));
  hn[cb + 16] = f2b(fmaxf(a1 * inv, 0.f));
  hn[cb + 32] = f2b(fmaxf(a2 * inv, 0.f));
  hn[cb + 48] = f2b(fmaxf(a3 * inv, 0.f));
}

// ================= TransE scoring: 16-lane groups, bf16 h (L2-resident), 2-deep unroll =================
__global__ void score4_kernel(const unsigned short* __restrict__ hb, const float* __restrict__ relf,
                              const int* __restrict__ ps2, const int* __restrict__ es_src,
                              const int* __restrict__ es_et, const int* __restrict__ es_eid,
                              float* __restrict__ out, int n){
  int w = threadIdx.x >> 6, lane = threadIdx.x & 63;
  int node = blockIdx.x * 4 + w;
  if (node >= n) return;
  const int g = lane >> 4, cl = lane & 15;        // group (edge slot), column-lane
  int kb = (node >> 5) * 1024 + (node & 31) * 32;
  int s0 = ps2[kb], s1 = ps2[kb + 32];
  // dst row: lane owns cols cl*16..cl*16+15, decoded to fp32 regs
  float dv[16];
  {
    const ushort4* hd = (const ushort4*)(hb + (size_t)node * H_);
    #pragma unroll
    for (int q = 0; q < 4; ++q){
      ushort4 a = hd[cl * 4 + q];
      dv[4*q+0] = b2f(a.x); dv[4*q+1] = b2f(a.y);
      dv[4*q+2] = b2f(a.z); dv[4*q+3] = b2f(a.w);
    }
  }

  auto edge_sum = [&](int j)->float{
    int sc = es_src[j], r = es_et[j];
    const ushort4* hs = (const ushort4*)(hb + (size_t)sc * H_);
    const float4*  rv = (const float4*)(relf + (size_t)r * H_);
    float sum = 0.f;
    #pragma unroll
    for (int q = 0; q < 4; ++q){
      ushort4 a = hs[cl * 4 + q];
      float4  b = rv[cl * 4 + q];
      sum += fabsf(b2f(a.x) + b.x - dv[4*q+0]) + fabsf(b2f(a.y) + b.y - dv[4*q+1])
           + fabsf(b2f(a.z) + b.z - dv[4*q+2]) + fabsf(b2f(a.w) + b.w - dv[4*q+3]);
    }
    return sum;
  };

  int j = s0 + g;
  for (; j + 4 < s1; j += 8){                     // 2 edges per group in flight
    float sA = edge_sum(j), sB = edge_sum(j + 4);
    #pragma unroll
    for (int o = 8; o; o >>= 1){ sA += __shfl_xor(sA, o); sB += __shfl_xor(sB, o); }
    if (!cl){ out[es_eid[j]] = GAMMA_ - sA; out[es_eid[j + 4]] = GAMMA_ - sB; }
  }
  if (j < s1){
    float sA = edge_sum(j);
    #pragma unroll
    for (int o = 8; o; o >>= 1) sA += __shfl_xor(sA, o);
    if (!cl) out[es_eid[j]] = GAMMA_ - sA;
  }
}

extern "C" void kernel_launch(void* const* d_in, const int* in_sizes, int n_in,
                              void* d_out, int out_size, void* d_ws, size_t ws_size,
                              hipStream_t stream){
  const float* x         = (const float*)d_in[0];
  const int*   edge_idx  = (const int*)d_in[1];
  const int*   edge_type = (const int*)d_in[2];
  const float* W1        = (const float*)d_in[3];
  const float* q1        = (const float*)d_in[4];
  const float* k1        = (const float*)d_in[5];
  const float* W2        = (const float*)d_in[6];
  const float* q2        = (const float*)d_in[7];
  const float* k2        = (const float*)d_in[8];
  const float* lin_w     = (const float*)d_in[9];
  const float* lin_b     = (const float*)d_in[10];
  const float* rel_bert  = (const float*)d_in[11];
  const float* rel_lin_w = (const float*)d_in[12];
  const float* rel_lin_b = (const float*)d_in[13];
  float* score = (float*)d_out;

  const int Nn = in_sizes[0] / H_;   // 10000
  const int E  = in_sizes[1] / 2;    // 320000
  const int* src_a = edge_idx;
  const int* dst_a = edge_idx + E;
  const int NBLK   = (Nn + 31) / 32;              // 313 dst-bin blocks
  const int NBINS  = NBLK * 1024;
  const int NB2    = (R_ * Nn + 1023) / 1024;     // 313 flag blocks
  const int NBINS2 = NB2 * 1024;

  // workspace carve-up (256B aligned)
  char* ws = (char*)d_ws;
  size_t cur_off = 0;
  auto carve = [&](size_t bytes)->char*{
    char* p = ws + cur_off;
    cur_off += (bytes + 255) & ~(size_t)255;
    return p;
  };
  unsigned char*  xt8  = (unsigned char*)carve((size_t)Nn * R_ * H_);      // fp8, worst case
  unsigned short* xb   = (unsigned short*)carve((size_t)Nn * H_ * 2);
  unsigned short* h1   = (unsigned short*)carve((size_t)Nn * H_ * 2);
  unsigned short* h2   = (unsigned short*)carve((size_t)Nn * H_ * 2);
  unsigned short* outb = (unsigned short*)carve((size_t)Nn * H_ * 2);
  unsigned short* Wt1  = (unsigned short*)carve((size_t)R_ * 65536 * 2);
  unsigned short* Wt2  = (unsigned short*)carve((size_t)R_ * 65536 * 2);
  unsigned short* linT = (unsigned short*)carve(65536 * 2);
  float* relf  = (float*)carve((size_t)R_ * H_ * 4);
  float* wqkT1 = (float*)carve(64 * H_ * 4);
  float* wqkT2 = (float*)carve(64 * H_ * 4);
  float* qdot  = (float*)carve((size_t)Nn * R_ * 4);
  float* kdot  = (float*)carve((size_t)Nn * R_ * 4);
  int* cnt2    = (int*)carve((size_t)NBINS * 4);
  int* cur2    = (int*)carve((size_t)NBINS * 4);
  int* flagA   = (int*)carve((size_t)NBINS2 * 4);
  int* tot     = (int*)carve((size_t)NBLK * 4);
  int* tot2    = (int*)carve((size_t)NB2 * 4);
  int* baseA   = (int*)carve((size_t)(NBLK + 1) * 4);
  int* base2   = (int*)carve((size_t)(NB2 + 1) * 4);
  int* ps2     = (int*)carve((size_t)(NBINS + 1) * 4);
  int* ps3     = (int*)carve((size_t)(NBINS2 + 1) * 4);
  int* nodelist= (int*)carve((size_t)(R_ * Nn) * 4);
  int* es_src  = (int*)carve((size_t)E * 4);
  int* es_row  = (int*)carve((size_t)E * 4);
  int* es_et   = (int*)carve((size_t)E * 4);
  int* es_eid  = (int*)carve((size_t)E * 4);
  float* attn  = (float*)carve((size_t)E * 4);
  (void)ws_size; (void)n_in; (void)out_size;

  const int mt = (Nn + 127) / 128;         // 79
  const int nqd = (Nn + 3) / 4;            // 2500

  // prep block ranges
  const int n4 = Nn * H_ / 4;
  const int nb0 = (n4 + 255) / 256, nb_tw = 2048, nb_lin = 64, nb_wqk = 2048, nb_rel = 32;
  const int nb_hist = (E + 255) / 256;
  const int nprep = nb0 + 2 * nb_tw + nb_lin + 2 * nb_wqk + nb_rel + nb_hist;

  hipMemsetAsync(cnt2, 0, (size_t)NBINS * 4, stream);
  hipMemsetAsync(cur2, 0, (size_t)NBINS * 4, stream);
  hipMemsetAsync(flagA, 0, (size_t)NBINS2 * 4, stream);

  prep_kernel<<<nprep, 256, 0, stream>>>(
      x, xb, n4, W1, Wt1, W2, Wt2, lin_w, linT,
      q1, k1, wqkT1, q2, k2, wqkT2,
      rel_bert, rel_lin_w, rel_lin_b, relf,
      src_a, dst_a, edge_type, cnt2, flagA, E, Nn,
      nb0, nb_tw, nb_lin, nb_wqk, nb_rel, nb_hist);

  totred_kernel<<<NBLK + NB2, 256, 0, stream>>>(cnt2, tot, flagA, tot2, NBLK);
  scan_kernel<<<1, 1024, 0, stream>>>(tot, baseA, NBLK, tot2, base2, NB2);
  ps2scan_kernel<<<NBLK + NB2, 256, 0, stream>>>(cnt2, baseA, ps2, NBLK, flagA, base2, ps3, NB2);
  nodelist_kernel<<<(NBINS2 + 255) / 256, 256, 0, stream>>>(flagA, ps3, nodelist, R_ * Nn, Nn);
  scatter2_kernel<<<(E + 255) / 256, 256, 0, stream>>>(src_a, dst_a, edge_type, ps2, ps3, cur2,
                                                       es_src, es_row, es_et, es_eid, E, Nn);

  // ---- layer 1 ----
  gemm3_kernel<0><<<R_ * mt, 512, 0, stream>>>(xb, Wt1, xt8, nullptr, Nn, mt, nodelist, ps3, Nn);
  qdot_kernel<<<nqd, 256, 0, stream>>>(xb, wqkT1, qdot, kdot, Nn);
  attn_agg_kernel<<<nqd, 256, 0, stream>>>(xt8, qdot, kdot, ps2, es_src, es_row, attn, h1, Nn);

  // ---- layer 2 ----
  gemm3_kernel<0><<<R_ * mt, 512, 0, stream>>>(h1, Wt2, xt8, nullptr, Nn, mt, nodelist, ps3, Nn);
  qdot_kernel<<<nqd, 256, 0, stream>>>(h1, wqkT2, qdot, kdot, Nn);
  attn_agg_kernel<<<nqd, 256, 0, stream>>>(xt8, qdot, kdot, ps2, es_src, es_row, attn, h2, Nn);

  // ---- final linear + scoring ----
  gemm3_kernel<1><<<mt, 512, 0, stream>>>(h2, linT, outb, lin_b, Nn, mt, nullptr, nullptr, Nn);
  score4_kernel<<<nqd, 256, 0, stream>>>(outb, relf, ps2, es_src, es_et, es_eid, score, Nn);
}

// Round 19
// 353.019 us; speedup vs baseline: 1.1057x; 1.0444x over previous
//
#include <hip/hip_runtime.h>
#include <hip/hip_bf16.h>
#include <stdint.h>

#define R_ 32
#define H_ 256
#define GAMMA_ 10.0f

typedef __attribute__((ext_vector_type(4))) float f32x4;
typedef __attribute__((ext_vector_type(2))) float f32x2;
typedef __attribute__((ext_vector_type(8))) short bf16x8;

__device__ __forceinline__ unsigned short f2b(float f){
  union { float f; unsigned u; } v; v.f = f;
  unsigned r = v.u + 0x7FFFu + ((v.u >> 16) & 1u);
  return (unsigned short)(r >> 16);
}
__device__ __forceinline__ float b2f(unsigned short h){
  union { unsigned u; float f; } v; v.u = ((unsigned)h) << 16; return v.f;
}

#if __has_builtin(__builtin_amdgcn_cvt_pk_fp8_f32) && __has_builtin(__builtin_amdgcn_cvt_pk_f32_fp8)
#define HWFP8 1
#else
#define HWFP8 0
__device__ __forceinline__ unsigned f2fp8(float f){
  unsigned s = (__float_as_uint(f) >> 24) & 0x80u;
  float a = fminf(fabsf(f), 448.f);
  unsigned b = __float_as_uint(a);
  b += 0x7FFFFu + ((b >> 20) & 1u);
  unsigned code = (((b >> 23) - 120u) << 3) | ((b >> 20) & 7u);
  code = (a < 0.015625f) ? 0u : code;
  return (s | code) & 0xFFu;
}
__device__ __forceinline__ float fp82f(unsigned c){
  unsigned E = (c >> 3) & 15u, m = c & 7u, s = (c >> 7) & 1u;
  unsigned bits = ((E + 120u) << 23) | (m << 20) | (s << 31);
  float v = __uint_as_float(bits);
  return (E == 0) ? 0.f : v;
}
#endif

__device__ __forceinline__ unsigned pack4_fp8(float a0, float a1, float a2, float a3){
#if HWFP8
  unsigned pk = (unsigned)__builtin_amdgcn_cvt_pk_fp8_f32(a0, a1, 0, false);
  pk = (unsigned)__builtin_amdgcn_cvt_pk_fp8_f32(a2, a3, (int)pk, true);
  return pk;
#else
  return f2fp8(a0) | (f2fp8(a1) << 8) | (f2fp8(a2) << 16) | (f2fp8(a3) << 24);
#endif
}
__device__ __forceinline__ f32x4 unpack4_fp8(unsigned w){
#if HWFP8
  f32x2 lo = __builtin_amdgcn_cvt_pk_f32_fp8((int)w, false);
  f32x2 hi = __builtin_amdgcn_cvt_pk_f32_fp8((int)w, true);
  f32x4 r; r[0] = lo[0]; r[1] = lo[1]; r[2] = hi[0]; r[3] = hi[1];
  return r;
#else
  f32x4 r;
  r[0] = fp82f(w & 255u); r[1] = fp82f((w >> 8) & 255u);
  r[2] = fp82f((w >> 16) & 255u); r[3] = fp82f(w >> 24);
  return r;
#endif
}

// ========= prep mega-kernel: rel(split-i, FIRST) | cvt | transw x3 | wqk x2 | hist+flag =========
__global__ __launch_bounds__(256) void prep_kernel(
    const float* __restrict__ x, unsigned short* __restrict__ xb, int n4,
    const float* __restrict__ W1, unsigned short* __restrict__ Wt1,
    const float* __restrict__ W2, unsigned short* __restrict__ Wt2,
    const float* __restrict__ lin_w, unsigned short* __restrict__ linT,
    const float* __restrict__ q1, const float* __restrict__ k1, float* __restrict__ wqkT1,
    const float* __restrict__ q2, const float* __restrict__ k2, float* __restrict__ wqkT2,
    const float* __restrict__ rb, const float* __restrict__ rw,
    const float* __restrict__ rbias, float* __restrict__ relf,
    const int* __restrict__ srcp, const int* __restrict__ dst, const int* __restrict__ et,
    int* __restrict__ cnt2, int* __restrict__ flagA, int E, int Nn,
    int nb_rel, int nb0, int nb_tw, int nb_lin, int nb_wqk, int nb_hist){
  __shared__ float tile[32][33];
  __shared__ float red[8][32];
  const int bx = blockIdx.x, t = threadIdx.x;
  const int b0 = nb_rel;                 // rel first (tail section overlaps the rest)
  const int b1 = b0 + nb0;               // cvt
  const int b2 = b1 + nb_tw;             // transw W1
  const int b3 = b2 + nb_tw;             // transw W2
  const int b4 = b3 + nb_lin;            // transw lin
  const int b5 = b4 + nb_wqk;            // wqk W1
  const int b6 = b5 + nb_wqk;            // wqk W2

  if (bx < b0){                          // ---- rel: 8 blocks per r, 8 i-groups x 32 h
    int r = bx >> 3, h0 = (bx & 7) * 32;
    int ig = t >> 5, hl = t & 31;
    int h = h0 + hl;
    const float* br = rb + (size_t)r * 768;
    float a0 = 0.f, a1 = 0.f, a2 = 0.f, a3 = 0.f;
    int ibase = ig * 96;
    #pragma unroll 4
    for (int i = 0; i < 96; i += 4){
      int ii = ibase + i;
      a0 = fmaf(br[ii + 0], rw[(size_t)(ii + 0) * 256 + h], a0);
      a1 = fmaf(br[ii + 1], rw[(size_t)(ii + 1) * 256 + h], a1);
      a2 = fmaf(br[ii + 2], rw[(size_t)(ii + 2) * 256 + h], a2);
      a3 = fmaf(br[ii + 3], rw[(size_t)(ii + 3) * 256 + h], a3);
    }
    red[ig][hl] = (a0 + a1) + (a2 + a3);
    __syncthreads();
    if (ig == 0){
      float s = 0.f;
      #pragma unroll
      for (int g2 = 0; g2 < 8; ++g2) s += red[g2][hl];
      relf[r * 256 + h] = fmaxf(s + rbias[h], 0.f);
    }
    return;
  }
  if (bx < b1){                          // ---- cvt fp32->bf16
    int i = (bx - b0) * 256 + t;
    if (i < n4){
      float4 v = ((const float4*)x)[i];
      ushort4 o; o.x=f2b(v.x); o.y=f2b(v.y); o.z=f2b(v.z); o.w=f2b(v.w);
      ((ushort4*)xb)[i] = o;
    }
    return;
  }
  if (bx < b4){                          // ---- transw (W1 | W2 | lin)
    const float* W; unsigned short* Wt; int local;
    if (bx < b2){ W = W1; Wt = Wt1; local = bx - b1; }
    else if (bx < b3){ W = W2; Wt = Wt2; local = bx - b2; }
    else { W = lin_w; Wt = linT; local = bx - b3; }
    int i0 = (local & 7) * 32, o0 = ((local >> 3) & 7) * 32, r = local >> 6;
    int tx = t & 31, ty = t >> 5;
    const float* Wr = W + (size_t)r * 65536;
    for (int rr = ty; rr < 32; rr += 8)
      tile[rr][tx] = Wr[(size_t)(i0 + rr) * 256 + o0 + tx];
    __syncthreads();
    unsigned short* outr = Wt + (size_t)r * 65536;
    for (int rr = ty; rr < 32; rr += 8)
      outr[(size_t)(o0 + rr) * 256 + i0 + tx] = f2b(tile[tx][rr]);
    return;
  }
  if (bx < b6){                          // ---- wqk (W1 | W2)
    bool first = bx < b5;
    int local = bx - (first ? b4 : b5);
    int w = t >> 6, lane = t & 63;
    int p = local * 4 + w;               // 0..8191
    int i = p & 255, r = p >> 8;
    const float* W  = first ? W1 : W2;
    const float* qv = first ? q1 : q2;
    const float* kv = first ? k1 : k2;
    const float* row = W + ((size_t)r * 256 + i) * 256;
    float sq = 0.f, sk = 0.f;
    #pragma unroll
    for (int q4 = 0; q4 < 4; ++q4){
      int o = lane + q4 * 64;
      float wv = row[o];
      sq += wv * qv[r * 256 + o];
      sk += wv * kv[r * 256 + o];
    }
    #pragma unroll
    for (int o = 32; o; o >>= 1){ sq += __shfl_xor(sq, o); sk += __shfl_xor(sk, o); }
    if (!lane){
      float* wq = first ? wqkT1 : wqkT2;
      wq[i * 64 + r] = sq; wq[i * 64 + 32 + r] = sk;
    }
    return;
  }
  {                                      // ---- hist (dst bins) + used-pair flag
    int e = (bx - b6) * 256 + t;
    if (e < E){
      int d = dst[e], r = et[e];
      atomicAdd(&cnt2[(d >> 5) * 1024 + (d & 31) * 32 + r], 1);
      flagA[r * Nn + srcp[e]] = 1;       // races write same value: fine
    }
  }
}

// ================= fused two-array scan chain =================
__global__ void totred_kernel(const int* __restrict__ cnt2, int* __restrict__ tot,
                              const int* __restrict__ flagA, int* __restrict__ tot2, int nblk1){
  __shared__ int red[256];
  int blk = blockIdx.x, t = threadIdx.x;
  const int* srcb = (blk < nblk1) ? (cnt2 + (size_t)blk * 1024) : (flagA + (size_t)(blk - nblk1) * 1024);
  int* dstb = (blk < nblk1) ? (tot + blk) : (tot2 + blk - nblk1);
  int s = 0;
  #pragma unroll
  for (int q = 0; q < 4; ++q) s += srcb[q * 256 + t];
  red[t] = s; __syncthreads();
  for (int o = 128; o; o >>= 1){ if (t < o) red[t] += red[t + o]; __syncthreads(); }
  if (!t) *dstb = red[0];
}
__device__ void scan_body(const int* deg, int* off, int n){
  __shared__ int carry;
  __shared__ int buf[1024];
  if (threadIdx.x == 0) carry = 0;
  __syncthreads();
  for (int base = 0; base < n; base += 1024){
    int i = base + threadIdx.x;
    int v = (i < n) ? deg[i] : 0;
    buf[threadIdx.x] = v; __syncthreads();
    for (int o = 1; o < 1024; o <<= 1){
      int t = (threadIdx.x >= o) ? buf[threadIdx.x - o] : 0;
      __syncthreads();
      buf[threadIdx.x] += t;
      __syncthreads();
    }
    if (i < n) off[i] = carry + buf[threadIdx.x] - v;   // exclusive
    __syncthreads();
    if (threadIdx.x == 1023) carry += buf[1023];
    __syncthreads();
  }
  if (threadIdx.x == 0) off[n] = carry;
  __syncthreads();
}
__global__ void scan_kernel(const int* __restrict__ d1, int* __restrict__ o1, int n1,
                            const int* __restrict__ d2, int* __restrict__ o2, int n2){
  scan_body(d1, o1, n1);
  scan_body(d2, o2, n2);
}
__global__ __launch_bounds__(256) void ps2scan_kernel(
    const int* __restrict__ cnt2, const int* __restrict__ base1, int* __restrict__ ps2, int nblk1,
    const int* __restrict__ flagA, const int* __restrict__ base2, int* __restrict__ ps3, int nblk2){
  __shared__ int sb[1024];
  int blk = blockIdx.x, t = threadIdx.x;
  const bool first = blk < nblk1;
  const int lb = first ? blk : blk - nblk1;
  const int* srcb = first ? (cnt2 + (size_t)lb * 1024) : (flagA + (size_t)lb * 1024);
  int* dstb = first ? (ps2 + (size_t)lb * 1024) : (ps3 + (size_t)lb * 1024);
  const int* base = first ? base1 : base2;
  int orig[4];
  #pragma unroll
  for (int q = 0; q < 4; ++q){ int i = q * 256 + t; orig[q] = srcb[i]; sb[i] = orig[q]; }
  __syncthreads();
  for (int o = 1; o < 1024; o <<= 1){
    int v[4];
    #pragma unroll
    for (int q = 0; q < 4; ++q){ int i = q * 256 + t; v[q] = (i >= o) ? sb[i - o] : 0; }
    __syncthreads();
    #pragma unroll
    for (int q = 0; q < 4; ++q){ int i = q * 256 + t; sb[i] += v[q]; }
    __syncthreads();
  }
  int b = base[lb];
  #pragma unroll
  for (int q = 0; q < 4; ++q){ int i = q * 256 + t; dstb[i] = b + sb[i] - orig[q]; }
  if (lb == 0 && t == 0){
    if (first) ps2[(size_t)nblk1 * 1024] = base1[nblk1];
    else       ps3[(size_t)nblk2 * 1024] = base2[nblk2];
  }
}
__global__ void nodelist_kernel(const int* __restrict__ flagA, const int* __restrict__ ps3,
                                int* __restrict__ nodelist, int ntot, int Nn){
  int i = blockIdx.x * 256 + threadIdx.x;
  if (i < ntot && flagA[i]) nodelist[ps3[i]] = i % Nn;
}
__global__ void scatter2_kernel(const int* __restrict__ src, const int* __restrict__ dst,
                                const int* __restrict__ et, const int* __restrict__ ps2,
                                const int* __restrict__ ps3, int* __restrict__ cur2,
                                int* __restrict__ es_src, int* __restrict__ es_row,
                                int* __restrict__ es_et, int* __restrict__ es_eid, int E, int Nn){
  int e = blockIdx.x * 256 + threadIdx.x;
  if (e >= E) return;
  int d = dst[e], r = et[e], s = src[e];
  int key = (d >> 5) * 1024 + (d & 31) * 32 + r;
  int pos = ps2[key] + atomicAdd(&cur2[key], 1);
  es_src[pos] = s;
  es_row[pos] = ps3[(size_t)r * Nn + s];          // compacted xt row for this edge
  es_et[pos]  = r;
  es_eid[pos] = e;
}

// ================= qdot standalone (4KB LDS, high occupancy) =================
__global__ void qdot_kernel(const unsigned short* __restrict__ xb, const float* __restrict__ wqkT,
                            float* __restrict__ qdot, float* __restrict__ kdot, int n){
  __shared__ float xrow[4][256];
  int w = threadIdx.x >> 6, lane = threadIdx.x & 63;
  int node = blockIdx.x * 4 + w;
  if (node >= n) return;
  ushort4 v = ((const ushort4*)(xb + (size_t)node * 256))[lane];
  float* xr = xrow[w];
  xr[lane * 4 + 0] = b2f(v.x);
  xr[lane * 4 + 1] = b2f(v.y);
  xr[lane * 4 + 2] = b2f(v.z);
  xr[lane * 4 + 3] = b2f(v.w);
  float acc = 0.f;
  #pragma unroll 8
  for (int kk = 0; kk < 256; ++kk)
    acc = fmaf(xr[kk], wqkT[kk * 64 + lane], acc);
  if (lane < 32) qdot[node * 32 + lane] = acc;
  else           kdot[node * 32 + lane - 32] = acc;
}

// ================= GEMM: BM=128 x BN=256; MODE0 -> fp8 packed-dword rows; MODE1 -> bf16+bias =================
template<int MODE>
__global__ __launch_bounds__(512) void gemm3_kernel(
    const unsigned short* __restrict__ A, const unsigned short* __restrict__ Bt,
    void* __restrict__ Cv, const float* __restrict__ bias, int M, int MT,
    const int* __restrict__ nodelist, const int* __restrict__ ps3, int Nn){
  __shared__ unsigned short As[2][128 * 64];
  __shared__ unsigned short Bs[2][256 * 64];
  __shared__ int rowsL[128];
  const int bx = blockIdx.x;
  const int r  = (MODE == 0) ? bx / MT : 0;
  const int mb = (MODE == 0) ? bx % MT : bx;
  int u0 = 0, u1 = M;
  if (MODE == 0){
    u0 = ps3[(size_t)r * Nn];
    u1 = ps3[(size_t)(r + 1) * Nn];
    if (mb * 128 >= u1 - u0) return;              // empty block for this relation
  }
  const int tid = threadIdx.x, lane = tid & 63, wid = tid >> 6;
  const int wm = (wid >> 2) * 64;
  const int wn = (wid & 3) * 64;
  const int lg = lane >> 4, lr = lane & 15;
  const unsigned short* Brel = Bt + (size_t)r * 65536;

  if (tid < 128){
    if (MODE == 0){
      int cr = u0 + mb * 128 + tid;
      if (cr >= u1) cr = u1 - 1;
      rowsL[tid] = nodelist[cr];
    } else {
      int g = mb * 128 + tid; if (g >= M) g = M - 1;
      rowsL[tid] = g;
    }
  }
  __syncthreads();

  f32x4 acc[4][4];
  #pragma unroll
  for (int i = 0; i < 4; ++i)
    #pragma unroll
    for (int j = 0; j < 4; ++j) acc[i][j] = (f32x4)0.0f;

  auto stage = [&](int buf, int kt){
    #pragma unroll
    for (int q = 0; q < 2; ++q){
      int ci = q * 512 + tid;
      int row = ci >> 3, p = ci & 7;
      int gch = p ^ (row & 7);                    // inverse-swizzled source
      const unsigned short* ga = A + (size_t)rowsL[row] * 256 + kt * 64 + gch * 8;
      __builtin_amdgcn_global_load_lds((const __attribute__((address_space(1))) void*)ga,
          (__attribute__((address_space(3))) void*)(As[buf] + (size_t)ci * 8), 16, 0, 0);
    }
    #pragma unroll
    for (int q = 0; q < 4; ++q){
      int ci = q * 512 + tid;
      int row = ci >> 3, p = ci & 7;
      int gch = p ^ (row & 7);
      const unsigned short* gb = Brel + (size_t)row * 256 + kt * 64 + gch * 8;
      __builtin_amdgcn_global_load_lds((const __attribute__((address_space(1))) void*)gb,
          (__attribute__((address_space(3))) void*)(Bs[buf] + (size_t)ci * 8), 16, 0, 0);
    }
  };

  stage(0, 0);
  __syncthreads();

  for (int kt = 0; kt < 4; ++kt){
    const int cur = kt & 1;
    if (kt < 3) stage(cur ^ 1, kt + 1);           // prefetch overlaps compute
    #pragma unroll
    for (int kk = 0; kk < 2; ++kk){
      bf16x8 af[4], bg[4];
      #pragma unroll
      for (int mi = 0; mi < 4; ++mi){
        int row = wm + mi * 16 + lr;
        int pc = (lg + kk * 4) ^ (row & 7);
        af[mi] = *(const bf16x8*)&As[cur][row * 64 + pc * 8];
      }
      #pragma unroll
      for (int ni = 0; ni < 4; ++ni){
        int row = wn + ni * 16 + lr;
        int pc = (lg + kk * 4) ^ (row & 7);
        bg[ni] = *(const bf16x8*)&Bs[cur][row * 64 + pc * 8];
      }
      #pragma unroll
      for (int mi = 0; mi < 4; ++mi)
        #pragma unroll
        for (int ni = 0; ni < 4; ++ni)
          acc[mi][ni] = __builtin_amdgcn_mfma_f32_16x16x32_bf16(af[mi], bg[ni], acc[mi][ni], 0, 0, 0);
    }
    __syncthreads();
  }

  // epilogue: C/D layout col=lane&15, row=(lane>>4)*4+reg
  if (MODE == 0){
    #pragma unroll
    for (int mi = 0; mi < 4; ++mi){
      #pragma unroll
      for (int j = 0; j < 4; ++j){
        int rowloc = wm + mi * 16 + lg * 4 + j;
        int cr = u0 + mb * 128 + rowloc;
        if (cr < u1){
          unsigned pk = pack4_fp8(acc[mi][0][j], acc[mi][1][j], acc[mi][2][j], acc[mi][3][j]);
          *(unsigned*)((unsigned char*)Cv + (size_t)cr * 256 + wn + lr * 4) = pk;
        }
      }
    }
  } else {
    #pragma unroll
    for (int mi = 0; mi < 4; ++mi){
      #pragma unroll
      for (int j = 0; j < 4; ++j){
        int rowm = mb * 128 + wm + mi * 16 + lg * 4 + j;
        if (rowm >= M) continue;
        #pragma unroll
        for (int ni = 0; ni < 4; ++ni){
          int col = wn + ni * 16 + lr;
          ((unsigned short*)Cv)[(size_t)rowm * H_ + col] = f2b(acc[mi][ni][j] + bias[col]);
        }
      }
    }
  }
}

// ================= fused softmax + aggregation: wave per node (packed fp8 xt) =================
__global__ void attn_agg_kernel(const unsigned char* __restrict__ xt8, const float* __restrict__ qdot,
                                const float* __restrict__ kdot, const int* __restrict__ ps2,
                                const int* __restrict__ es_src, const int* __restrict__ es_row,
                                float* __restrict__ a, unsigned short* __restrict__ hout, int n){
  int w = threadIdx.x >> 6, lane = threadIdx.x & 63;
  int node = blockIdx.x * 4 + w;
  if (node >= n) return;
  int kb = (node >> 5) * 1024 + (node & 31) * 32;
  // ---- phase A: softmax stats; lane r owns the node's (et=r) run; store raw exp
  int s = 0, e = 0;
  float qd = 0.f;
  if (lane < 32){
    s = ps2[kb + lane]; e = ps2[kb + lane + 1];
    qd = qdot[node * 32 + lane];
  }
  float m = -1e30f;
  for (int j = s; j < e; ++j){
    float z = qd + kdot[es_src[j] * 32 + lane];
    z = (z > 0.f) ? z : 0.2f * z;          // leaky_relu 0.2
    a[j] = z;
    m = fmaxf(m, z);
  }
  #pragma unroll
  for (int o = 32; o; o >>= 1) m = fmaxf(m, __shfl_xor(m, o));
  float sum = 0.f;
  for (int j = s; j < e; ++j){
    float ez = __expf(a[j] - m);
    a[j] = ez; sum += ez;
  }
  #pragma unroll
  for (int o = 32; o; o >>= 1) sum += __shfl_xor(sum, o);
  float inv = 1.0f / (sum + 1e-16f);
  // ---- phase B: aggregate; lane L's dword (bytes 4L..4L+3) = cols (4L&192)+k*16+(L&15)
  int s0 = ps2[kb], s1 = ps2[kb + 32];
  float a0 = 0.f, a1 = 0.f, a2 = 0.f, a3 = 0.f;
  int j = s0;
  for (; j + 2 <= s1; j += 2){
    int r0 = es_row[j], r1 = es_row[j+1];
    float w0 = a[j], w1 = a[j+1];
    unsigned v0 = ((const unsigned*)(xt8 + (size_t)r0 * 256))[lane];
    unsigned v1 = ((const unsigned*)(xt8 + (size_t)r1 * 256))[lane];
    f32x4 d0 = unpack4_fp8(v0), d1 = unpack4_fp8(v1);
    a0 += w0*d0[0] + w1*d1[0];
    a1 += w0*d0[1] + w1*d1[1];
    a2 += w0*d0[2] + w1*d1[2];
    a3 += w0*d0[3] + w1*d1[3];
  }
  for (; j < s1; ++j){
    float wv = a[j];
    unsigned v = ((const unsigned*)(xt8 + (size_t)es_row[j] * 256))[lane];
    f32x4 d = unpack4_fp8(v);
    a0 = fmaf(wv, d[0], a0);
    a1 = fmaf(wv, d[1], a1);
    a2 = fmaf(wv, d[2], a2);
    a3 = fmaf(wv, d[3], a3);
  }
  // hout: actual col for byte k = (lane&48)*4 + k*16 + (lane&15)
  int cb = ((lane & 48) << 2) + (lane & 15);
  unsigned short* hn = hout + (size_t)node * H_;
  hn[cb +  0] = f2b(fmaxf(a0 * inv, 0.f));
  hn[cb + 16] = f2b(fmaxf(a1 * inv, 0.f));
  hn[cb + 32] = f2b(fmaxf(a2 * inv, 0.f));
  hn[cb + 48] = f2b(fmaxf(a3 * inv, 0.f));
}

// ================= TransE scoring: 16-lane groups, bf16 h (L2-resident), 2-deep unroll =================
__global__ void score4_kernel(const unsigned short* __restrict__ hb, const float* __restrict__ relf,
                              const int* __restrict__ ps2, const int* __restrict__ es_src,
                              const int* __restrict__ es_et, const int* __restrict__ es_eid,
                              float* __restrict__ out, int n){
  int w = threadIdx.x >> 6, lane = threadIdx.x & 63;
  int node = blockIdx.x * 4 + w;
  if (node >= n) return;
  const int g = lane >> 4, cl = lane & 15;        // group (edge slot), column-lane
  int kb = (node >> 5) * 1024 + (node & 31) * 32;
  int s0 = ps2[kb], s1 = ps2[kb + 32];
  // dst row: lane owns cols cl*16..cl*16+15, decoded to fp32 regs
  float dv[16];
  {
    const ushort4* hd = (const ushort4*)(hb + (size_t)node * H_);
    #pragma unroll
    for (int q = 0; q < 4; ++q){
      ushort4 a = hd[cl * 4 + q];
      dv[4*q+0] = b2f(a.x); dv[4*q+1] = b2f(a.y);
      dv[4*q+2] = b2f(a.z); dv[4*q+3] = b2f(a.w);
    }
  }

  auto edge_sum = [&](int j)->float{
    int sc = es_src[j], r = es_et[j];
    const ushort4* hs = (const ushort4*)(hb + (size_t)sc * H_);
    const float4*  rv = (const float4*)(relf + (size_t)r * H_);
    float sum = 0.f;
    #pragma unroll
    for (int q = 0; q < 4; ++q){
      ushort4 a = hs[cl * 4 + q];
      float4  b = rv[cl * 4 + q];
      sum += fabsf(b2f(a.x) + b.x - dv[4*q+0]) + fabsf(b2f(a.y) + b.y - dv[4*q+1])
           + fabsf(b2f(a.z) + b.z - dv[4*q+2]) + fabsf(b2f(a.w) + b.w - dv[4*q+3]);
    }
    return sum;
  };

  int j = s0 + g;
  for (; j + 4 < s1; j += 8){                     // 2 edges per group in flight
    float sA = edge_sum(j), sB = edge_sum(j + 4);
    #pragma unroll
    for (int o = 8; o; o >>= 1){ sA += __shfl_xor(sA, o); sB += __shfl_xor(sB, o); }
    if (!cl){ out[es_eid[j]] = GAMMA_ - sA; out[es_eid[j + 4]] = GAMMA_ - sB; }
  }
  if (j < s1){
    float sA = edge_sum(j);
    #pragma unroll
    for (int o = 8; o; o >>= 1) sA += __shfl_xor(sA, o);
    if (!cl) out[es_eid[j]] = GAMMA_ - sA;
  }
}

extern "C" void kernel_launch(void* const* d_in, const int* in_sizes, int n_in,
                              void* d_out, int out_size, void* d_ws, size_t ws_size,
                              hipStream_t stream){
  const float* x         = (const float*)d_in[0];
  const int*   edge_idx  = (const int*)d_in[1];
  const int*   edge_type = (const int*)d_in[2];
  const float* W1        = (const float*)d_in[3];
  const float* q1        = (const float*)d_in[4];
  const float* k1        = (const float*)d_in[5];
  const float* W2        = (const float*)d_in[6];
  const float* q2        = (const float*)d_in[7];
  const float* k2        = (const float*)d_in[8];
  const float* lin_w     = (const float*)d_in[9];
  const float* lin_b     = (const float*)d_in[10];
  const float* rel_bert  = (const float*)d_in[11];
  const float* rel_lin_w = (const float*)d_in[12];
  const float* rel_lin_b = (const float*)d_in[13];
  float* score = (float*)d_out;

  const int Nn = in_sizes[0] / H_;   // 10000
  const int E  = in_sizes[1] / 2;    // 320000
  const int* src_a = edge_idx;
  const int* dst_a = edge_idx + E;
  const int NBLK   = (Nn + 31) / 32;              // 313 dst-bin blocks
  const int NBINS  = NBLK * 1024;
  const int NB2    = (R_ * Nn + 1023) / 1024;     // 313 flag blocks
  const int NBINS2 = NB2 * 1024;

  // workspace carve-up (256B aligned)
  char* ws = (char*)d_ws;
  size_t cur_off = 0;
  auto carve = [&](size_t bytes)->char*{
    char* p = ws + cur_off;
    cur_off += (bytes + 255) & ~(size_t)255;
    return p;
  };
  unsigned char*  xt8  = (unsigned char*)carve((size_t)Nn * R_ * H_);      // fp8, worst case
  unsigned short* xb   = (unsigned short*)carve((size_t)Nn * H_ * 2);
  unsigned short* h1   = (unsigned short*)carve((size_t)Nn * H_ * 2);
  unsigned short* h2   = (unsigned short*)carve((size_t)Nn * H_ * 2);
  unsigned short* outb = (unsigned short*)carve((size_t)Nn * H_ * 2);
  unsigned short* Wt1  = (unsigned short*)carve((size_t)R_ * 65536 * 2);
  unsigned short* Wt2  = (unsigned short*)carve((size_t)R_ * 65536 * 2);
  unsigned short* linT = (unsigned short*)carve(65536 * 2);
  float* relf  = (float*)carve((size_t)R_ * H_ * 4);
  float* wqkT1 = (float*)carve(64 * H_ * 4);
  float* wqkT2 = (float*)carve(64 * H_ * 4);
  float* qdot  = (float*)carve((size_t)Nn * R_ * 4);
  float* kdot  = (float*)carve((size_t)Nn * R_ * 4);
  int* cnt2    = (int*)carve((size_t)NBINS * 4);
  int* cur2    = (int*)carve((size_t)NBINS * 4);
  int* flagA   = (int*)carve((size_t)NBINS2 * 4);
  int* tot     = (int*)carve((size_t)NBLK * 4);
  int* tot2    = (int*)carve((size_t)NB2 * 4);
  int* baseA   = (int*)carve((size_t)(NBLK + 1) * 4);
  int* base2   = (int*)carve((size_t)(NB2 + 1) * 4);
  int* ps2     = (int*)carve((size_t)(NBINS + 1) * 4);
  int* ps3     = (int*)carve((size_t)(NBINS2 + 1) * 4);
  int* nodelist= (int*)carve((size_t)(R_ * Nn) * 4);
  int* es_src  = (int*)carve((size_t)E * 4);
  int* es_row  = (int*)carve((size_t)E * 4);
  int* es_et   = (int*)carve((size_t)E * 4);
  int* es_eid  = (int*)carve((size_t)E * 4);
  float* attn  = (float*)carve((size_t)E * 4);
  (void)ws_size; (void)n_in; (void)out_size;

  const int mt = (Nn + 127) / 128;         // 79
  const int nqd = (Nn + 3) / 4;            // 2500

  // prep block ranges (rel first — tail section overlaps the rest)
  const int n4 = Nn * H_ / 4;
  const int nb_rel = 256, nb0 = (n4 + 255) / 256, nb_tw = 2048, nb_lin = 64, nb_wqk = 2048;
  const int nb_hist = (E + 255) / 256;
  const int nprep = nb_rel + nb0 + 2 * nb_tw + nb_lin + 2 * nb_wqk + nb_hist;

  hipMemsetAsync(cnt2, 0, (size_t)NBINS * 4, stream);
  hipMemsetAsync(cur2, 0, (size_t)NBINS * 4, stream);
  hipMemsetAsync(flagA, 0, (size_t)NBINS2 * 4, stream);

  prep_kernel<<<nprep, 256, 0, stream>>>(
      x, xb, n4, W1, Wt1, W2, Wt2, lin_w, linT,
      q1, k1, wqkT1, q2, k2, wqkT2,
      rel_bert, rel_lin_w, rel_lin_b, relf,
      src_a, dst_a, edge_type, cnt2, flagA, E, Nn,
      nb_rel, nb0, nb_tw, nb_lin, nb_wqk, nb_hist);

  totred_kernel<<<NBLK + NB2, 256, 0, stream>>>(cnt2, tot, flagA, tot2, NBLK);
  scan_kernel<<<1, 1024, 0, stream>>>(tot, baseA, NBLK, tot2, base2, NB2);
  ps2scan_kernel<<<NBLK + NB2, 256, 0, stream>>>(cnt2, baseA, ps2, NBLK, flagA, base2, ps3, NB2);
  nodelist_kernel<<<(NBINS2 + 255) / 256, 256, 0, stream>>>(flagA, ps3, nodelist, R_ * Nn, Nn);
  scatter2_kernel<<<(E + 255) / 256, 256, 0, stream>>>(src_a, dst_a, edge_type, ps2, ps3, cur2,
                                                       es_src, es_row, es_et, es_eid, E, Nn);

  // ---- layer 1 ----
  gemm3_kernel<0><<<R_ * mt, 512, 0, stream>>>(xb, Wt1, xt8, nullptr, Nn, mt, nodelist, ps3, Nn);
  qdot_kernel<<<nqd, 256, 0, stream>>>(xb, wqkT1, qdot, kdot, Nn);
  attn_agg_kernel<<<nqd, 256, 0, stream>>>(xt8, qdot, kdot, ps2, es_src, es_row, attn, h1, Nn);

  // ---- layer 2 ----
  gemm3_kernel<0><<<R_ * mt, 512, 0, stream>>>(h1, Wt2, xt8, nullptr, Nn, mt, nodelist, ps3, Nn);
  qdot_kernel<<<nqd, 256, 0, stream>>>(h1, wqkT2, qdot, kdot, Nn);
  attn_agg_kernel<<<nqd, 256, 0, stream>>>(xt8, qdot, kdot, ps2, es_src, es_row, attn, h2, Nn);

  // ---- final linear + scoring ----
  gemm3_kernel<1><<<mt, 512, 0, stream>>>(h2, linT, outb, lin_b, Nn, mt, nullptr, nullptr, Nn);
  score4_kernel<<<nqd, 256, 0, stream>>>(outb, relf, ps2, es_src, es_et, es_eid, score, Nn);
}

// Round 20
// 336.967 us; speedup vs baseline: 1.1583x; 1.0476x over previous
//
#include <hip/hip_runtime.h>
#include <hip/hip_bf16.h>
#include <stdint.h>

#define R_ 32
#define H_ 256
#define GAMMA_ 10.0f

typedef __attribute__((ext_vector_type(4))) float f32x4;
typedef __attribute__((ext_vector_type(2))) float f32x2;
typedef __attribute__((ext_vector_type(8))) short bf16x8;

__device__ __forceinline__ unsigned short f2b(float f){
  union { float f; unsigned u; } v; v.f = f;
  unsigned r = v.u + 0x7FFFu + ((v.u >> 16) & 1u);
  return (unsigned short)(r >> 16);
}
__device__ __forceinline__ float b2f(unsigned short h){
  union { unsigned u; float f; } v; v.u = ((unsigned)h) << 16; return v.f;
}

#if __has_builtin(__builtin_amdgcn_cvt_pk_fp8_f32) && __has_builtin(__builtin_amdgcn_cvt_pk_f32_fp8)
#define HWFP8 1
#else
#define HWFP8 0
__device__ __forceinline__ unsigned f2fp8(float f){
  unsigned s = (__float_as_uint(f) >> 24) & 0x80u;
  float a = fminf(fabsf(f), 448.f);
  unsigned b = __float_as_uint(a);
  b += 0x7FFFFu + ((b >> 20) & 1u);
  unsigned code = (((b >> 23) - 120u) << 3) | ((b >> 20) & 7u);
  code = (a < 0.015625f) ? 0u : code;
  return (s | code) & 0xFFu;
}
__device__ __forceinline__ float fp82f(unsigned c){
  unsigned E = (c >> 3) & 15u, m = c & 7u, s = (c >> 7) & 1u;
  unsigned bits = ((E + 120u) << 23) | (m << 20) | (s << 31);
  float v = __uint_as_float(bits);
  return (E == 0) ? 0.f : v;
}
#endif

__device__ __forceinline__ unsigned pack4_fp8(float a0, float a1, float a2, float a3){
#if HWFP8
  unsigned pk = (unsigned)__builtin_amdgcn_cvt_pk_fp8_f32(a0, a1, 0, false);
  pk = (unsigned)__builtin_amdgcn_cvt_pk_fp8_f32(a2, a3, (int)pk, true);
  return pk;
#else
  return f2fp8(a0) | (f2fp8(a1) << 8) | (f2fp8(a2) << 16) | (f2fp8(a3) << 24);
#endif
}
__device__ __forceinline__ f32x4 unpack4_fp8(unsigned w){
#if HWFP8
  f32x2 lo = __builtin_amdgcn_cvt_pk_f32_fp8((int)w, false);
  f32x2 hi = __builtin_amdgcn_cvt_pk_f32_fp8((int)w, true);
  f32x4 r; r[0] = lo[0]; r[1] = lo[1]; r[2] = hi[0]; r[3] = hi[1];
  return r;
#else
  f32x4 r;
  r[0] = fp82f(w & 255u); r[1] = fp82f((w >> 8) & 255u);
  r[2] = fp82f((w >> 16) & 255u); r[3] = fp82f(w >> 24);
  return r;
#endif
}

// ========= prep mega-kernel: rel(split-i, FIRST) | cvt | transw x3 | wqk x2 | hist+flag =========
__global__ __launch_bounds__(256) void prep_kernel(
    const float* __restrict__ x, unsigned short* __restrict__ xb, int n4,
    const float* __restrict__ W1, unsigned short* __restrict__ Wt1,
    const float* __restrict__ W2, unsigned short* __restrict__ Wt2,
    const float* __restrict__ lin_w, unsigned short* __restrict__ linT,
    const float* __restrict__ q1, const float* __restrict__ k1, float* __restrict__ wqkT1,
    const float* __restrict__ q2, const float* __restrict__ k2, float* __restrict__ wqkT2,
    const float* __restrict__ rb, const float* __restrict__ rw,
    const float* __restrict__ rbias, float* __restrict__ relf,
    const int* __restrict__ srcp, const int* __restrict__ dst, const int* __restrict__ et,
    int* __restrict__ cnt2, int* __restrict__ flagA, int E, int Nn,
    int nb_rel, int nb0, int nb_tw, int nb_lin, int nb_wqk, int nb_hist){
  __shared__ float tile[32][33];
  __shared__ float red[8][32];
  const int bx = blockIdx.x, t = threadIdx.x;
  const int b0 = nb_rel;                 // rel first (tail section overlaps the rest)
  const int b1 = b0 + nb0;               // cvt
  const int b2 = b1 + nb_tw;             // transw W1
  const int b3 = b2 + nb_tw;             // transw W2
  const int b4 = b3 + nb_lin;            // transw lin
  const int b5 = b4 + nb_wqk;            // wqk W1
  const int b6 = b5 + nb_wqk;            // wqk W2

  if (bx < b0){                          // ---- rel: 8 blocks per r, 8 i-groups x 32 h
    int r = bx >> 3, h0 = (bx & 7) * 32;
    int ig = t >> 5, hl = t & 31;
    int h = h0 + hl;
    const float* br = rb + (size_t)r * 768;
    float a0 = 0.f, a1 = 0.f, a2 = 0.f, a3 = 0.f;
    int ibase = ig * 96;
    #pragma unroll 4
    for (int i = 0; i < 96; i += 4){
      int ii = ibase + i;
      a0 = fmaf(br[ii + 0], rw[(size_t)(ii + 0) * 256 + h], a0);
      a1 = fmaf(br[ii + 1], rw[(size_t)(ii + 1) * 256 + h], a1);
      a2 = fmaf(br[ii + 2], rw[(size_t)(ii + 2) * 256 + h], a2);
      a3 = fmaf(br[ii + 3], rw[(size_t)(ii + 3) * 256 + h], a3);
    }
    red[ig][hl] = (a0 + a1) + (a2 + a3);
    __syncthreads();
    if (ig == 0){
      float s = 0.f;
      #pragma unroll
      for (int g2 = 0; g2 < 8; ++g2) s += red[g2][hl];
      relf[r * 256 + h] = fmaxf(s + rbias[h], 0.f);
    }
    return;
  }
  if (bx < b1){                          // ---- cvt fp32->bf16
    int i = (bx - b0) * 256 + t;
    if (i < n4){
      float4 v = ((const float4*)x)[i];
      ushort4 o; o.x=f2b(v.x); o.y=f2b(v.y); o.z=f2b(v.z); o.w=f2b(v.w);
      ((ushort4*)xb)[i] = o;
    }
    return;
  }
  if (bx < b4){                          // ---- transw (W1 | W2 | lin)
    const float* W; unsigned short* Wt; int local;
    if (bx < b2){ W = W1; Wt = Wt1; local = bx - b1; }
    else if (bx < b3){ W = W2; Wt = Wt2; local = bx - b2; }
    else { W = lin_w; Wt = linT; local = bx - b3; }
    int i0 = (local & 7) * 32, o0 = ((local >> 3) & 7) * 32, r = local >> 6;
    int tx = t & 31, ty = t >> 5;
    const float* Wr = W + (size_t)r * 65536;
    for (int rr = ty; rr < 32; rr += 8)
      tile[rr][tx] = Wr[(size_t)(i0 + rr) * 256 + o0 + tx];
    __syncthreads();
    unsigned short* outr = Wt + (size_t)r * 65536;
    for (int rr = ty; rr < 32; rr += 8)
      outr[(size_t)(o0 + rr) * 256 + i0 + tx] = f2b(tile[tx][rr]);
    return;
  }
  if (bx < b6){                          // ---- wqk (W1 | W2)
    bool first = bx < b5;
    int local = bx - (first ? b4 : b5);
    int w = t >> 6, lane = t & 63;
    int p = local * 4 + w;               // 0..8191
    int i = p & 255, r = p >> 8;
    const float* W  = first ? W1 : W2;
    const float* qv = first ? q1 : q2;
    const float* kv = first ? k1 : k2;
    const float* row = W + ((size_t)r * 256 + i) * 256;
    float sq = 0.f, sk = 0.f;
    #pragma unroll
    for (int q4 = 0; q4 < 4; ++q4){
      int o = lane + q4 * 64;
      float wv = row[o];
      sq += wv * qv[r * 256 + o];
      sk += wv * kv[r * 256 + o];
    }
    #pragma unroll
    for (int o = 32; o; o >>= 1){ sq += __shfl_xor(sq, o); sk += __shfl_xor(sk, o); }
    if (!lane){
      float* wq = first ? wqkT1 : wqkT2;
      wq[i * 64 + r] = sq; wq[i * 64 + 32 + r] = sk;
    }
    return;
  }
  {                                      // ---- hist (dst bins) + used-pair flag
    int e = (bx - b6) * 256 + t;
    if (e < E){
      int d = dst[e], r = et[e];
      atomicAdd(&cnt2[(d >> 5) * 1024 + (d & 31) * 32 + r], 1);
      flagA[r * Nn + srcp[e]] = 1;       // races write same value: fine
    }
  }
}

// ================= fused two-array scan chain =================
__global__ void totred_kernel(const int* __restrict__ cnt2, int* __restrict__ tot,
                              const int* __restrict__ flagA, int* __restrict__ tot2, int nblk1){
  __shared__ int red[256];
  int blk = blockIdx.x, t = threadIdx.x;
  const int* srcb = (blk < nblk1) ? (cnt2 + (size_t)blk * 1024) : (flagA + (size_t)(blk - nblk1) * 1024);
  int* dstb = (blk < nblk1) ? (tot + blk) : (tot2 + blk - nblk1);
  int s = 0;
  #pragma unroll
  for (int q = 0; q < 4; ++q) s += srcb[q * 256 + t];
  red[t] = s; __syncthreads();
  for (int o = 128; o; o >>= 1){ if (t < o) red[t] += red[t + o]; __syncthreads(); }
  if (!t) *dstb = red[0];
}
__device__ void scan_body(const int* deg, int* off, int n){
  __shared__ int carry;
  __shared__ int buf[1024];
  if (threadIdx.x == 0) carry = 0;
  __syncthreads();
  for (int base = 0; base < n; base += 1024){
    int i = base + threadIdx.x;
    int v = (i < n) ? deg[i] : 0;
    buf[threadIdx.x] = v; __syncthreads();
    for (int o = 1; o < 1024; o <<= 1){
      int t = (threadIdx.x >= o) ? buf[threadIdx.x - o] : 0;
      __syncthreads();
      buf[threadIdx.x] += t;
      __syncthreads();
    }
    if (i < n) off[i] = carry + buf[threadIdx.x] - v;   // exclusive
    __syncthreads();
    if (threadIdx.x == 1023) carry += buf[1023];
    __syncthreads();
  }
  if (threadIdx.x == 0) off[n] = carry;
  __syncthreads();
}
__global__ void scan_kernel(const int* __restrict__ d1, int* __restrict__ o1, int n1,
                            const int* __restrict__ d2, int* __restrict__ o2, int n2){
  scan_body(d1, o1, n1);
  scan_body(d2, o2, n2);
}
__global__ __launch_bounds__(256) void ps2scan_kernel(
    const int* __restrict__ cnt2, const int* __restrict__ base1, int* __restrict__ ps2, int nblk1,
    const int* __restrict__ flagA, const int* __restrict__ base2, int* __restrict__ ps3, int nblk2){
  __shared__ int sb[1024];
  int blk = blockIdx.x, t = threadIdx.x;
  const bool first = blk < nblk1;
  const int lb = first ? blk : blk - nblk1;
  const int* srcb = first ? (cnt2 + (size_t)lb * 1024) : (flagA + (size_t)lb * 1024);
  int* dstb = first ? (ps2 + (size_t)lb * 1024) : (ps3 + (size_t)lb * 1024);
  const int* base = first ? base1 : base2;
  int orig[4];
  #pragma unroll
  for (int q = 0; q < 4; ++q){ int i = q * 256 + t; orig[q] = srcb[i]; sb[i] = orig[q]; }
  __syncthreads();
  for (int o = 1; o < 1024; o <<= 1){
    int v[4];
    #pragma unroll
    for (int q = 0; q < 4; ++q){ int i = q * 256 + t; v[q] = (i >= o) ? sb[i - o] : 0; }
    __syncthreads();
    #pragma unroll
    for (int q = 0; q < 4; ++q){ int i = q * 256 + t; sb[i] += v[q]; }
    __syncthreads();
  }
  int b = base[lb];
  #pragma unroll
  for (int q = 0; q < 4; ++q){ int i = q * 256 + t; dstb[i] = b + sb[i] - orig[q]; }
  if (lb == 0 && t == 0){
    if (first) ps2[(size_t)nblk1 * 1024] = base1[nblk1];
    else       ps3[(size_t)nblk2 * 1024] = base2[nblk2];
  }
}
__global__ void nodelist_kernel(const int* __restrict__ flagA, const int* __restrict__ ps3,
                                int* __restrict__ nodelist, int ntot, int Nn){
  int i = blockIdx.x * 256 + threadIdx.x;
  if (i < ntot && flagA[i]) nodelist[ps3[i]] = i % Nn;
}
__global__ void scatter2_kernel(const int* __restrict__ src, const int* __restrict__ dst,
                                const int* __restrict__ et, const int* __restrict__ ps2,
                                const int* __restrict__ ps3, int* __restrict__ cur2,
                                int* __restrict__ es_src, int* __restrict__ es_row,
                                int* __restrict__ es_et, int* __restrict__ es_eid, int E, int Nn){
  int e = blockIdx.x * 256 + threadIdx.x;
  if (e >= E) return;
  int d = dst[e], r = et[e], s = src[e];
  int key = (d >> 5) * 1024 + (d & 31) * 32 + r;
  int pos = ps2[key] + atomicAdd(&cur2[key], 1);
  es_src[pos] = s;
  es_row[pos] = ps3[(size_t)r * Nn + s];          // compacted xt row for this edge
  es_et[pos]  = r;
  es_eid[pos] = e;
}

// ================= qdot standalone (4KB LDS, high occupancy) =================
__global__ void qdot_kernel(const unsigned short* __restrict__ xb, const float* __restrict__ wqkT,
                            float* __restrict__ qdot, float* __restrict__ kdot, int n){
  __shared__ float xrow[4][256];
  int w = threadIdx.x >> 6, lane = threadIdx.x & 63;
  int node = blockIdx.x * 4 + w;
  if (node >= n) return;
  ushort4 v = ((const ushort4*)(xb + (size_t)node * 256))[lane];
  float* xr = xrow[w];
  xr[lane * 4 + 0] = b2f(v.x);
  xr[lane * 4 + 1] = b2f(v.y);
  xr[lane * 4 + 2] = b2f(v.z);
  xr[lane * 4 + 3] = b2f(v.w);
  float acc = 0.f;
  #pragma unroll 8
  for (int kk = 0; kk < 256; ++kk)
    acc = fmaf(xr[kk], wqkT[kk * 64 + lane], acc);
  if (lane < 32) qdot[node * 32 + lane] = acc;
  else           kdot[node * 32 + lane - 32] = acc;
}

// ===== GEMM: BM=128 x BN=256, BK=32 (48KB LDS -> 3 blocks/CU); MODE0 fp8-packed; MODE1 bf16+bias =====
template<int MODE>
__global__ __launch_bounds__(512) void gemm3_kernel(
    const unsigned short* __restrict__ A, const unsigned short* __restrict__ Bt,
    void* __restrict__ Cv, const float* __restrict__ bias, int M, int MT,
    const int* __restrict__ nodelist, const int* __restrict__ ps3, int Nn){
  __shared__ unsigned short As[2][128 * 32];
  __shared__ unsigned short Bs[2][256 * 32];
  __shared__ int rowsL[128];
  const int bx = blockIdx.x;
  const int r  = (MODE == 0) ? bx / MT : 0;
  const int mb = (MODE == 0) ? bx % MT : bx;
  int u0 = 0, u1 = M;
  if (MODE == 0){
    u0 = ps3[(size_t)r * Nn];
    u1 = ps3[(size_t)(r + 1) * Nn];
    if (mb * 128 >= u1 - u0) return;              // empty block for this relation
  }
  const int tid = threadIdx.x, lane = tid & 63, wid = tid >> 6;
  const int wm = (wid >> 2) * 64;
  const int wn = (wid & 3) * 64;
  const int lg = lane >> 4, lr = lane & 15;
  const unsigned short* Brel = Bt + (size_t)r * 65536;

  if (tid < 128){
    if (MODE == 0){
      int cr = u0 + mb * 128 + tid;
      if (cr >= u1) cr = u1 - 1;
      rowsL[tid] = nodelist[cr];
    } else {
      int g = mb * 128 + tid; if (g >= M) g = M - 1;
      rowsL[tid] = g;
    }
  }
  __syncthreads();

  f32x4 acc[4][4];
  #pragma unroll
  for (int i = 0; i < 4; ++i)
    #pragma unroll
    for (int j = 0; j < 4; ++j) acc[i][j] = (f32x4)0.0f;

  auto stage = [&](int buf, int kt){
    // A tile: 128 rows x 32 k = 512 x 16B chunks (1 per thread); 4 chunks/row, ^(row&3) swizzle
    {
      int ci = tid;
      int row = ci >> 2, p = ci & 3;
      int gch = p ^ (row & 3);                    // inverse-swizzled source
      const unsigned short* ga = A + (size_t)rowsL[row] * 256 + kt * 32 + gch * 8;
      __builtin_amdgcn_global_load_lds((const __attribute__((address_space(1))) void*)ga,
          (__attribute__((address_space(3))) void*)(As[buf] + (size_t)ci * 8), 16, 0, 0);
    }
    // B tile: 256 rows x 32 k = 1024 x 16B chunks (2 per thread)
    #pragma unroll
    for (int q = 0; q < 2; ++q){
      int ci = q * 512 + tid;
      int row = ci >> 2, p = ci & 3;
      int gch = p ^ (row & 3);
      const unsigned short* gb = Brel + (size_t)row * 256 + kt * 32 + gch * 8;
      __builtin_amdgcn_global_load_lds((const __attribute__((address_space(1))) void*)gb,
          (__attribute__((address_space(3))) void*)(Bs[buf] + (size_t)ci * 8), 16, 0, 0);
    }
  };

  stage(0, 0);
  __syncthreads();

  for (int kt = 0; kt < 8; ++kt){
    const int cur = kt & 1;
    if (kt < 7) stage(cur ^ 1, kt + 1);           // prefetch overlaps compute
    bf16x8 af[4], bg[4];
    #pragma unroll
    for (int mi = 0; mi < 4; ++mi){
      int row = wm + mi * 16 + lr;
      int pc = lg ^ (row & 3);
      af[mi] = *(const bf16x8*)&As[cur][row * 32 + pc * 8];
    }
    #pragma unroll
    for (int ni = 0; ni < 4; ++ni){
      int row = wn + ni * 16 + lr;
      int pc = lg ^ (row & 3);
      bg[ni] = *(const bf16x8*)&Bs[cur][row * 32 + pc * 8];
    }
    #pragma unroll
    for (int mi = 0; mi < 4; ++mi)
      #pragma unroll
      for (int ni = 0; ni < 4; ++ni)
        acc[mi][ni] = __builtin_amdgcn_mfma_f32_16x16x32_bf16(af[mi], bg[ni], acc[mi][ni], 0, 0, 0);
    __syncthreads();
  }

  // epilogue: C/D layout col=lane&15, row=(lane>>4)*4+reg
  if (MODE == 0){
    #pragma unroll
    for (int mi = 0; mi < 4; ++mi){
      #pragma unroll
      for (int j = 0; j < 4; ++j){
        int rowloc = wm + mi * 16 + lg * 4 + j;
        int cr = u0 + mb * 128 + rowloc;
        if (cr < u1){
          unsigned pk = pack4_fp8(acc[mi][0][j], acc[mi][1][j], acc[mi][2][j], acc[mi][3][j]);
          *(unsigned*)((unsigned char*)Cv + (size_t)cr * 256 + wn + lr * 4) = pk;
        }
      }
    }
  } else {
    #pragma unroll
    for (int mi = 0; mi < 4; ++mi){
      #pragma unroll
      for (int j = 0; j < 4; ++j){
        int rowm = mb * 128 + wm + mi * 16 + lg * 4 + j;
        if (rowm >= M) continue;
        #pragma unroll
        for (int ni = 0; ni < 4; ++ni){
          int col = wn + ni * 16 + lr;
          ((unsigned short*)Cv)[(size_t)rowm * H_ + col] = f2b(acc[mi][ni][j] + bias[col]);
        }
      }
    }
  }
}

// ================= fused softmax + aggregation: wave per node (packed fp8 xt) =================
__global__ void attn_agg_kernel(const unsigned char* __restrict__ xt8, const float* __restrict__ qdot,
                                const float* __restrict__ kdot, const int* __restrict__ ps2,
                                const int* __restrict__ es_src, const int* __restrict__ es_row,
                                float* __restrict__ a, unsigned short* __restrict__ hout, int n){
  int w = threadIdx.x >> 6, lane = threadIdx.x & 63;
  int node = blockIdx.x * 4 + w;
  if (node >= n) return;
  int kb = (node >> 5) * 1024 + (node & 31) * 32;
  // ---- phase A: softmax stats; lane r owns the node's (et=r) run; store raw exp
  int s = 0, e = 0;
  float qd = 0.f;
  if (lane < 32){
    s = ps2[kb + lane]; e = ps2[kb + lane + 1];
    qd = qdot[node * 32 + lane];
  }
  float m = -1e30f;
  for (int j = s; j < e; ++j){
    float z = qd + kdot[es_src[j] * 32 + lane];
    z = (z > 0.f) ? z : 0.2f * z;          // leaky_relu 0.2
    a[j] = z;
    m = fmaxf(m, z);
  }
  #pragma unroll
  for (int o = 32; o; o >>= 1) m = fmaxf(m, __shfl_xor(m, o));
  float sum = 0.f;
  for (int j = s; j < e; ++j){
    float ez = __expf(a[j] - m);
    a[j] = ez; sum += ez;
  }
  #pragma unroll
  for (int o = 32; o; o >>= 1) sum += __shfl_xor(sum, o);
  float inv = 1.0f / (sum + 1e-16f);
  // ---- phase B: aggregate; lane L's dword (bytes 4L..4L+3) = cols (4L&192)+k*16+(L&15)
  int s0 = ps2[kb], s1 = ps2[kb + 32];
  float a0 = 0.f, a1 = 0.f, a2 = 0.f, a3 = 0.f;
  int j = s0;
  for (; j + 2 <= s1; j += 2){
    int r0 = es_row[j], r1 = es_row[j+1];
    float w0 = a[j], w1 = a[j+1];
    unsigned v0 = ((const unsigned*)(xt8 + (size_t)r0 * 256))[lane];
    unsigned v1 = ((const unsigned*)(xt8 + (size_t)r1 * 256))[lane];
    f32x4 d0 = unpack4_fp8(v0), d1 = unpack4_fp8(v1);
    a0 += w0*d0[0] + w1*d1[0];
    a1 += w0*d0[1] + w1*d1[1];
    a2 += w0*d0[2] + w1*d1[2];
    a3 += w0*d0[3] + w1*d1[3];
  }
  for (; j < s1; ++j){
    float wv = a[j];
    unsigned v = ((const unsigned*)(xt8 + (size_t)es_row[j] * 256))[lane];
    f32x4 d = unpack4_fp8(v);
    a0 = fmaf(wv, d[0], a0);
    a1 = fmaf(wv, d[1], a1);
    a2 = fmaf(wv, d[2], a2);
    a3 = fmaf(wv, d[3], a3);
  }
  // hout: actual col for byte k = (lane&48)*4 + k*16 + (lane&15)
  int cb = ((lane & 48) << 2) + (lane & 15);
  unsigned short* hn = hout + (size_t)node * H_;
  hn[cb +  0] = f2b(fmaxf(a0 * inv, 0.f));
  hn[cb + 16] = f2b(fmaxf(a1 * inv, 0.f));
  hn[cb + 32] = f2b(fmaxf(a2 * inv, 0.f));
  hn[cb + 48] = f2b(fmaxf(a3 * inv, 0.f));
}

// ================= TransE scoring: 16-lane groups, bf16 h (L2-resident), 2-deep unroll =================
__global__ void score4_kernel(const unsigned short* __restrict__ hb, const float* __restrict__ relf,
                              const int* __restrict__ ps2, const int* __restrict__ es_src,
                              const int* __restrict__ es_et, const int* __restrict__ es_eid,
                              float* __restrict__ out, int n){
  int w = threadIdx.x >> 6, lane = threadIdx.x & 63;
  int node = blockIdx.x * 4 + w;
  if (node >= n) return;
  const int g = lane >> 4, cl = lane & 15;        // group (edge slot), column-lane
  int kb = (node >> 5) * 1024 + (node & 31) * 32;
  int s0 = ps2[kb], s1 = ps2[kb + 32];
  // dst row: lane owns cols cl*16..cl*16+15, decoded to fp32 regs
  float dv[16];
  {
    const ushort4* hd = (const ushort4*)(hb + (size_t)node * H_);
    #pragma unroll
    for (int q = 0; q < 4; ++q){
      ushort4 a = hd[cl * 4 + q];
      dv[4*q+0] = b2f(a.x); dv[4*q+1] = b2f(a.y);
      dv[4*q+2] = b2f(a.z); dv[4*q+3] = b2f(a.w);
    }
  }

  auto edge_sum = [&](int j)->float{
    int sc = es_src[j], r = es_et[j];
    const ushort4* hs = (const ushort4*)(hb + (size_t)sc * H_);
    const float4*  rv = (const float4*)(relf + (size_t)r * H_);
    float sum = 0.f;
    #pragma unroll
    for (int q = 0; q < 4; ++q){
      ushort4 a = hs[cl * 4 + q];
      float4  b = rv[cl * 4 + q];
      sum += fabsf(b2f(a.x) + b.x - dv[4*q+0]) + fabsf(b2f(a.y) + b.y - dv[4*q+1])
           + fabsf(b2f(a.z) + b.z - dv[4*q+2]) + fabsf(b2f(a.w) + b.w - dv[4*q+3]);
    }
    return sum;
  };

  int j = s0 + g;
  for (; j + 4 < s1; j += 8){                     // 2 edges per group in flight
    float sA = edge_sum(j), sB = edge_sum(j + 4);
    #pragma unroll
    for (int o = 8; o; o >>= 1){ sA += __shfl_xor(sA, o); sB += __shfl_xor(sB, o); }
    if (!cl){ out[es_eid[j]] = GAMMA_ - sA; out[es_eid[j + 4]] = GAMMA_ - sB; }
  }
  if (j < s1){
    float sA = edge_sum(j);
    #pragma unroll
    for (int o = 8; o; o >>= 1) sA += __shfl_xor(sA, o);
    if (!cl) out[es_eid[j]] = GAMMA_ - sA;
  }
}

extern "C" void kernel_launch(void* const* d_in, const int* in_sizes, int n_in,
                              void* d_out, int out_size, void* d_ws, size_t ws_size,
                              hipStream_t stream){
  const float* x         = (const float*)d_in[0];
  const int*   edge_idx  = (const int*)d_in[1];
  const int*   edge_type = (const int*)d_in[2];
  const float* W1        = (const float*)d_in[3];
  const float* q1        = (const float*)d_in[4];
  const float* k1        = (const float*)d_in[5];
  const float* W2        = (const float*)d_in[6];
  const float* q2        = (const float*)d_in[7];
  const float* k2        = (const float*)d_in[8];
  const float* lin_w     = (const float*)d_in[9];
  const float* lin_b     = (const float*)d_in[10];
  const float* rel_bert  = (const float*)d_in[11];
  const float* rel_lin_w = (const float*)d_in[12];
  const float* rel_lin_b = (const float*)d_in[13];
  float* score = (float*)d_out;

  const int Nn = in_sizes[0] / H_;   // 10000
  const int E  = in_sizes[1] / 2;    // 320000
  const int* src_a = edge_idx;
  const int* dst_a = edge_idx + E;
  const int NBLK   = (Nn + 31) / 32;              // 313 dst-bin blocks
  const int NBINS  = NBLK * 1024;
  const int NB2    = (R_ * Nn + 1023) / 1024;     // 313 flag blocks
  const int NBINS2 = NB2 * 1024;

  // workspace carve-up (256B aligned)
  char* ws = (char*)d_ws;
  size_t cur_off = 0;
  auto carve = [&](size_t bytes)->char*{
    char* p = ws + cur_off;
    cur_off += (bytes + 255) & ~(size_t)255;
    return p;
  };
  unsigned char*  xt8  = (unsigned char*)carve((size_t)Nn * R_ * H_);      // fp8, worst case
  unsigned short* xb   = (unsigned short*)carve((size_t)Nn * H_ * 2);
  unsigned short* h1   = (unsigned short*)carve((size_t)Nn * H_ * 2);
  unsigned short* h2   = (unsigned short*)carve((size_t)Nn * H_ * 2);
  unsigned short* outb = (unsigned short*)carve((size_t)Nn * H_ * 2);
  unsigned short* Wt1  = (unsigned short*)carve((size_t)R_ * 65536 * 2);
  unsigned short* Wt2  = (unsigned short*)carve((size_t)R_ * 65536 * 2);
  unsigned short* linT = (unsigned short*)carve(65536 * 2);
  float* relf  = (float*)carve((size_t)R_ * H_ * 4);
  float* wqkT1 = (float*)carve(64 * H_ * 4);
  float* wqkT2 = (float*)carve(64 * H_ * 4);
  float* qdot  = (float*)carve((size_t)Nn * R_ * 4);
  float* kdot  = (float*)carve((size_t)Nn * R_ * 4);
  int* cnt2    = (int*)carve((size_t)NBINS * 4);
  int* cur2    = (int*)carve((size_t)NBINS * 4);
  int* flagA   = (int*)carve((size_t)NBINS2 * 4);
  int* tot     = (int*)carve((size_t)NBLK * 4);
  int* tot2    = (int*)carve((size_t)NB2 * 4);
  int* baseA   = (int*)carve((size_t)(NBLK + 1) * 4);
  int* base2   = (int*)carve((size_t)(NB2 + 1) * 4);
  int* ps2     = (int*)carve((size_t)(NBINS + 1) * 4);
  int* ps3     = (int*)carve((size_t)(NBINS2 + 1) * 4);
  int* nodelist= (int*)carve((size_t)(R_ * Nn) * 4);
  int* es_src  = (int*)carve((size_t)E * 4);
  int* es_row  = (int*)carve((size_t)E * 4);
  int* es_et   = (int*)carve((size_t)E * 4);
  int* es_eid  = (int*)carve((size_t)E * 4);
  float* attn  = (float*)carve((size_t)E * 4);
  (void)ws_size; (void)n_in; (void)out_size;

  const int mt = (Nn + 127) / 128;         // 79
  const int nqd = (Nn + 3) / 4;            // 2500

  // prep block ranges (rel first — tail section overlaps the rest)
  const int n4 = Nn * H_ / 4;
  const int nb_rel = 256, nb0 = (n4 + 255) / 256, nb_tw = 2048, nb_lin = 64, nb_wqk = 2048;
  const int nb_hist = (E + 255) / 256;
  const int nprep = nb_rel + nb0 + 2 * nb_tw + nb_lin + 2 * nb_wqk + nb_hist;

  hipMemsetAsync(cnt2, 0, (size_t)NBINS * 4, stream);
  hipMemsetAsync(cur2, 0, (size_t)NBINS * 4, stream);
  hipMemsetAsync(flagA, 0, (size_t)NBINS2 * 4, stream);

  prep_kernel<<<nprep, 256, 0, stream>>>(
      x, xb, n4, W1, Wt1, W2, Wt2, lin_w, linT,
      q1, k1, wqkT1, q2, k2, wqkT2,
      rel_bert, rel_lin_w, rel_lin_b, relf,
      src_a, dst_a, edge_type, cnt2, flagA, E, Nn,
      nb_rel, nb0, nb_tw, nb_lin, nb_wqk, nb_hist);

  totred_kernel<<<NBLK + NB2, 256, 0, stream>>>(cnt2, tot, flagA, tot2, NBLK);
  scan_kernel<<<1, 1024, 0, stream>>>(tot, baseA, NBLK, tot2, base2, NB2);
  ps2scan_kernel<<<NBLK + NB2, 256, 0, stream>>>(cnt2, baseA, ps2, NBLK, flagA, base2, ps3, NB2);
  nodelist_kernel<<<(NBINS2 + 255) / 256, 256, 0, stream>>>(flagA, ps3, nodelist, R_ * Nn, Nn);
  scatter2_kernel<<<(E + 255) / 256, 256, 0, stream>>>(src_a, dst_a, edge_type, ps2, ps3, cur2,
                                                       es_src, es_row, es_et, es_eid, E, Nn);

  // ---- layer 1 ----
  gemm3_kernel<0><<<R_ * mt, 512, 0, stream>>>(xb, Wt1, xt8, nullptr, Nn, mt, nodelist, ps3, Nn);
  qdot_kernel<<<nqd, 256, 0, stream>>>(xb, wqkT1, qdot, kdot, Nn);
  attn_agg_kernel<<<nqd, 256, 0, stream>>>(xt8, qdot, kdot, ps2, es_src, es_row, attn, h1, Nn);

  // ---- layer 2 ----
  gemm3_kernel<0><<<R_ * mt, 512, 0, stream>>>(h1, Wt2, xt8, nullptr, Nn, mt, nodelist, ps3, Nn);
  qdot_kernel<<<nqd, 256, 0, stream>>>(h1, wqkT2, qdot, kdot, Nn);
  attn_agg_kernel<<<nqd, 256, 0, stream>>>(xt8, qdot, kdot, ps2, es_src, es_row, attn, h2, Nn);

  // ---- final linear + scoring ----
  gemm3_kernel<1><<<mt, 512, 0, stream>>>(h2, linT, outb, lin_b, Nn, mt, nullptr, nullptr, Nn);
  score4_kernel<<<nqd, 256, 0, stream>>>(outb, relf, ps2, es_src, es_et, es_eid, score, Nn);
}

// Round 21
// 330.966 us; speedup vs baseline: 1.1793x; 1.0181x over previous
//
#include <hip/hip_runtime.h>
#include <hip/hip_bf16.h>
#include <stdint.h>

#define R_ 32
#define H_ 256
#define GAMMA_ 10.0f

typedef __attribute__((ext_vector_type(4))) float f32x4;
typedef __attribute__((ext_vector_type(2))) float f32x2;
typedef __attribute__((ext_vector_type(8))) short bf16x8;

__device__ __forceinline__ unsigned short f2b(float f){
  union { float f; unsigned u; } v; v.f = f;
  unsigned r = v.u + 0x7FFFu + ((v.u >> 16) & 1u);
  return (unsigned short)(r >> 16);
}
__device__ __forceinline__ float b2f(unsigned short h){
  union { unsigned u; float f; } v; v.u = ((unsigned)h) << 16; return v.f;
}

#if __has_builtin(__builtin_amdgcn_cvt_pk_fp8_f32) && __has_builtin(__builtin_amdgcn_cvt_pk_f32_fp8)
#define HWFP8 1
#else
#define HWFP8 0
__device__ __forceinline__ unsigned f2fp8(float f){
  unsigned s = (__float_as_uint(f) >> 24) & 0x80u;
  float a = fminf(fabsf(f), 448.f);
  unsigned b = __float_as_uint(a);
  b += 0x7FFFFu + ((b >> 20) & 1u);
  unsigned code = (((b >> 23) - 120u) << 3) | ((b >> 20) & 7u);
  code = (a < 0.015625f) ? 0u : code;
  return (s | code) & 0xFFu;
}
__device__ __forceinline__ float fp82f(unsigned c){
  unsigned E = (c >> 3) & 15u, m = c & 7u, s = (c >> 7) & 1u;
  unsigned bits = ((E + 120u) << 23) | (m << 20) | (s << 31);
  float v = __uint_as_float(bits);
  return (E == 0) ? 0.f : v;
}
#endif

__device__ __forceinline__ unsigned pack4_fp8(float a0, float a1, float a2, float a3){
#if HWFP8
  unsigned pk = (unsigned)__builtin_amdgcn_cvt_pk_fp8_f32(a0, a1, 0, false);
  pk = (unsigned)__builtin_amdgcn_cvt_pk_fp8_f32(a2, a3, (int)pk, true);
  return pk;
#else
  return f2fp8(a0) | (f2fp8(a1) << 8) | (f2fp8(a2) << 16) | (f2fp8(a3) << 24);
#endif
}
__device__ __forceinline__ f32x4 unpack4_fp8(unsigned w){
#if HWFP8
  f32x2 lo = __builtin_amdgcn_cvt_pk_f32_fp8((int)w, false);
  f32x2 hi = __builtin_amdgcn_cvt_pk_f32_fp8((int)w, true);
  f32x4 r; r[0] = lo[0]; r[1] = lo[1]; r[2] = hi[0]; r[3] = hi[1];
  return r;
#else
  f32x4 r;
  r[0] = fp82f(w & 255u); r[1] = fp82f((w >> 8) & 255u);
  r[2] = fp82f((w >> 16) & 255u); r[3] = fp82f(w >> 24);
  return r;
#endif
}

// ========= prep mega-kernel: rel(split-i, FIRST) | cvt | transw x3 | wqk x2 | hist+flag =========
__global__ __launch_bounds__(256) void prep_kernel(
    const float* __restrict__ x, unsigned short* __restrict__ xb, int n4,
    const float* __restrict__ W1, unsigned short* __restrict__ Wt1,
    const float* __restrict__ W2, unsigned short* __restrict__ Wt2,
    const float* __restrict__ lin_w, unsigned short* __restrict__ linT,
    const float* __restrict__ q1, const float* __restrict__ k1, float* __restrict__ wqkT1,
    const float* __restrict__ q2, const float* __restrict__ k2, float* __restrict__ wqkT2,
    const float* __restrict__ rb, const float* __restrict__ rw,
    const float* __restrict__ rbias, float* __restrict__ relf,
    const int* __restrict__ srcp, const int* __restrict__ dst, const int* __restrict__ et,
    int* __restrict__ cnt2, int* __restrict__ flagA, int E, int Nn,
    int nb_rel, int nb0, int nb_tw, int nb_lin, int nb_wqk, int nb_hist){
  __shared__ float tile[32][33];
  __shared__ float red[8][32];
  const int bx = blockIdx.x, t = threadIdx.x;
  const int b0 = nb_rel;                 // rel first (tail section overlaps the rest)
  const int b1 = b0 + nb0;               // cvt
  const int b2 = b1 + nb_tw;             // transw W1
  const int b3 = b2 + nb_tw;             // transw W2
  const int b4 = b3 + nb_lin;            // transw lin
  const int b5 = b4 + nb_wqk;            // wqk W1
  const int b6 = b5 + nb_wqk;            // wqk W2

  if (bx < b0){                          // ---- rel: 8 blocks per r, 8 i-groups x 32 h
    int r = bx >> 3, h0 = (bx & 7) * 32;
    int ig = t >> 5, hl = t & 31;
    int h = h0 + hl;
    const float* br = rb + (size_t)r * 768;
    float a0 = 0.f, a1 = 0.f, a2 = 0.f, a3 = 0.f;
    int ibase = ig * 96;
    #pragma unroll 4
    for (int i = 0; i < 96; i += 4){
      int ii = ibase + i;
      a0 = fmaf(br[ii + 0], rw[(size_t)(ii + 0) * 256 + h], a0);
      a1 = fmaf(br[ii + 1], rw[(size_t)(ii + 1) * 256 + h], a1);
      a2 = fmaf(br[ii + 2], rw[(size_t)(ii + 2) * 256 + h], a2);
      a3 = fmaf(br[ii + 3], rw[(size_t)(ii + 3) * 256 + h], a3);
    }
    red[ig][hl] = (a0 + a1) + (a2 + a3);
    __syncthreads();
    if (ig == 0){
      float s = 0.f;
      #pragma unroll
      for (int g2 = 0; g2 < 8; ++g2) s += red[g2][hl];
      relf[r * 256 + h] = fmaxf(s + rbias[h], 0.f);
    }
    return;
  }
  if (bx < b1){                          // ---- cvt fp32->bf16
    int i = (bx - b0) * 256 + t;
    if (i < n4){
      float4 v = ((const float4*)x)[i];
      ushort4 o; o.x=f2b(v.x); o.y=f2b(v.y); o.z=f2b(v.z); o.w=f2b(v.w);
      ((ushort4*)xb)[i] = o;
    }
    return;
  }
  if (bx < b4){                          // ---- transw (W1 | W2 | lin)
    const float* W; unsigned short* Wt; int local;
    if (bx < b2){ W = W1; Wt = Wt1; local = bx - b1; }
    else if (bx < b3){ W = W2; Wt = Wt2; local = bx - b2; }
    else { W = lin_w; Wt = linT; local = bx - b3; }
    int i0 = (local & 7) * 32, o0 = ((local >> 3) & 7) * 32, r = local >> 6;
    int tx = t & 31, ty = t >> 5;
    const float* Wr = W + (size_t)r * 65536;
    for (int rr = ty; rr < 32; rr += 8)
      tile[rr][tx] = Wr[(size_t)(i0 + rr) * 256 + o0 + tx];
    __syncthreads();
    unsigned short* outr = Wt + (size_t)r * 65536;
    for (int rr = ty; rr < 32; rr += 8)
      outr[(size_t)(o0 + rr) * 256 + i0 + tx] = f2b(tile[tx][rr]);
    return;
  }
  if (bx < b6){                          // ---- wqk (W1 | W2)
    bool first = bx < b5;
    int local = bx - (first ? b4 : b5);
    int w = t >> 6, lane = t & 63;
    int p = local * 4 + w;               // 0..8191
    int i = p & 255, r = p >> 8;
    const float* W  = first ? W1 : W2;
    const float* qv = first ? q1 : q2;
    const float* kv = first ? k1 : k2;
    const float* row = W + ((size_t)r * 256 + i) * 256;
    float sq = 0.f, sk = 0.f;
    #pragma unroll
    for (int q4 = 0; q4 < 4; ++q4){
      int o = lane + q4 * 64;
      float wv = row[o];
      sq += wv * qv[r * 256 + o];
      sk += wv * kv[r * 256 + o];
    }
    #pragma unroll
    for (int o = 32; o; o >>= 1){ sq += __shfl_xor(sq, o); sk += __shfl_xor(sk, o); }
    if (!lane){
      float* wq = first ? wqkT1 : wqkT2;
      wq[i * 64 + r] = sq; wq[i * 64 + 32 + r] = sk;
    }
    return;
  }
  {                                      // ---- hist (dst bins) + used-pair flag
    int e = (bx - b6) * 256 + t;
    if (e < E){
      int d = dst[e], r = et[e];
      atomicAdd(&cnt2[(d >> 5) * 1024 + (d & 31) * 32 + r], 1);
      flagA[r * Nn + srcp[e]] = 1;       // races write same value: fine
    }
  }
}

// ================= fused two-array scan chain =================
__global__ void totred_kernel(const int* __restrict__ cnt2, int* __restrict__ tot,
                              const int* __restrict__ flagA, int* __restrict__ tot2, int nblk1){
  __shared__ int red[256];
  int blk = blockIdx.x, t = threadIdx.x;
  const int* srcb = (blk < nblk1) ? (cnt2 + (size_t)blk * 1024) : (flagA + (size_t)(blk - nblk1) * 1024);
  int* dstb = (blk < nblk1) ? (tot + blk) : (tot2 + blk - nblk1);
  int s = 0;
  #pragma unroll
  for (int q = 0; q < 4; ++q) s += srcb[q * 256 + t];
  red[t] = s; __syncthreads();
  for (int o = 128; o; o >>= 1){ if (t < o) red[t] += red[t + o]; __syncthreads(); }
  if (!t) *dstb = red[0];
}
__device__ void scan_body(const int* deg, int* off, int n){
  __shared__ int carry;
  __shared__ int buf[1024];
  if (threadIdx.x == 0) carry = 0;
  __syncthreads();
  for (int base = 0; base < n; base += 1024){
    int i = base + threadIdx.x;
    int v = (i < n) ? deg[i] : 0;
    buf[threadIdx.x] = v; __syncthreads();
    for (int o = 1; o < 1024; o <<= 1){
      int t = (threadIdx.x >= o) ? buf[threadIdx.x - o] : 0;
      __syncthreads();
      buf[threadIdx.x] += t;
      __syncthreads();
    }
    if (i < n) off[i] = carry + buf[threadIdx.x] - v;   // exclusive
    __syncthreads();
    if (threadIdx.x == 1023) carry += buf[1023];
    __syncthreads();
  }
  if (threadIdx.x == 0) off[n] = carry;
  __syncthreads();
}
__global__ void scan_kernel(const int* __restrict__ d1, int* __restrict__ o1, int n1,
                            const int* __restrict__ d2, int* __restrict__ o2, int n2){
  scan_body(d1, o1, n1);
  scan_body(d2, o2, n2);
}
__global__ __launch_bounds__(256) void ps2scan_kernel(
    const int* __restrict__ cnt2, const int* __restrict__ base1, int* __restrict__ ps2, int nblk1,
    const int* __restrict__ flagA, const int* __restrict__ base2, int* __restrict__ ps3, int nblk2){
  __shared__ int sb[1024];
  int blk = blockIdx.x, t = threadIdx.x;
  const bool first = blk < nblk1;
  const int lb = first ? blk : blk - nblk1;
  const int* srcb = first ? (cnt2 + (size_t)lb * 1024) : (flagA + (size_t)lb * 1024);
  int* dstb = first ? (ps2 + (size_t)lb * 1024) : (ps3 + (size_t)lb * 1024);
  const int* base = first ? base1 : base2;
  int orig[4];
  #pragma unroll
  for (int q = 0; q < 4; ++q){ int i = q * 256 + t; orig[q] = srcb[i]; sb[i] = orig[q]; }
  __syncthreads();
  for (int o = 1; o < 1024; o <<= 1){
    int v[4];
    #pragma unroll
    for (int q = 0; q < 4; ++q){ int i = q * 256 + t; v[q] = (i >= o) ? sb[i - o] : 0; }
    __syncthreads();
    #pragma unroll
    for (int q = 0; q < 4; ++q){ int i = q * 256 + t; sb[i] += v[q]; }
    __syncthreads();
  }
  int b = base[lb];
  #pragma unroll
  for (int q = 0; q < 4; ++q){ int i = q * 256 + t; dstb[i] = b + sb[i] - orig[q]; }
  if (lb == 0 && t == 0){
    if (first) ps2[(size_t)nblk1 * 1024] = base1[nblk1];
    else       ps3[(size_t)nblk2 * 1024] = base2[nblk2];
  }
}
__global__ void nodelist_kernel(const int* __restrict__ flagA, const int* __restrict__ ps3,
                                int* __restrict__ nodelist, int ntot, int Nn){
  int i = blockIdx.x * 256 + threadIdx.x;
  if (i < ntot && flagA[i]) nodelist[ps3[i]] = i % Nn;
}
__global__ void scatter2_kernel(const int* __restrict__ src, const int* __restrict__ dst,
                                const int* __restrict__ et, const int* __restrict__ ps2,
                                const int* __restrict__ ps3, int* __restrict__ cur2,
                                int* __restrict__ es_src, int* __restrict__ es_row,
                                int* __restrict__ es_et, int* __restrict__ es_eid, int E, int Nn){
  int e = blockIdx.x * 256 + threadIdx.x;
  if (e >= E) return;
  int d = dst[e], r = et[e], s = src[e];
  int key = (d >> 5) * 1024 + (d & 31) * 32 + r;
  int pos = ps2[key] + atomicAdd(&cur2[key], 1);
  es_src[pos] = s;
  es_row[pos] = ps3[(size_t)r * Nn + s];          // compacted xt row for this edge
  es_et[pos]  = r;
  es_eid[pos] = e;
}

// ================= qdot standalone (4KB LDS, high occupancy) =================
__global__ void qdot_kernel(const unsigned short* __restrict__ xb, const float* __restrict__ wqkT,
                            float* __restrict__ qdot, float* __restrict__ kdot, int n){
  __shared__ float xrow[4][256];
  int w = threadIdx.x >> 6, lane = threadIdx.x & 63;
  int node = blockIdx.x * 4 + w;
  if (node >= n) return;
  ushort4 v = ((const ushort4*)(xb + (size_t)node * 256))[lane];
  float* xr = xrow[w];
  xr[lane * 4 + 0] = b2f(v.x);
  xr[lane * 4 + 1] = b2f(v.y);
  xr[lane * 4 + 2] = b2f(v.z);
  xr[lane * 4 + 3] = b2f(v.w);
  float acc = 0.f;
  #pragma unroll 8
  for (int kk = 0; kk < 256; ++kk)
    acc = fmaf(xr[kk], wqkT[kk * 64 + lane], acc);
  if (lane < 32) qdot[node * 32 + lane] = acc;
  else           kdot[node * 32 + lane - 32] = acc;
}

// ===== GEMM: BM=128 x BN=256, BK=32 (48KB LDS -> 3 blocks/CU); MODE0 fp8-packed, m-major grid =====
// MODE0 decode: r = bx & 31 (XCD = bx%8 = r%8 -> B r-slice pinned per XCD), mb = bx >> 5.
template<int MODE>
__global__ __launch_bounds__(512) void gemm3_kernel(
    const unsigned short* __restrict__ A, const unsigned short* __restrict__ Bt,
    void* __restrict__ Cv, const float* __restrict__ bias, int M, int MT,
    const int* __restrict__ nodelist, const int* __restrict__ ps3, int Nn){
  __shared__ unsigned short As[2][128 * 32];
  __shared__ unsigned short Bs[2][256 * 32];
  __shared__ int rowsL[128];
  const int bx = blockIdx.x;
  const int r  = (MODE == 0) ? (bx & 31) : 0;     // m-major: B-slice pinned to XCD
  const int mb = (MODE == 0) ? (bx >> 5) : bx;
  int u0 = 0, u1 = M;
  if (MODE == 0){
    u0 = ps3[(size_t)r * Nn];
    u1 = ps3[(size_t)(r + 1) * Nn];
    if (mb * 128 >= u1 - u0) return;              // empty block for this relation
  }
  const int tid = threadIdx.x, lane = tid & 63, wid = tid >> 6;
  const int wm = (wid >> 2) * 64;
  const int wn = (wid & 3) * 64;
  const int lg = lane >> 4, lr = lane & 15;
  const unsigned short* Brel = Bt + (size_t)r * 65536;

  if (tid < 128){
    if (MODE == 0){
      int cr = u0 + mb * 128 + tid;
      if (cr >= u1) cr = u1 - 1;
      rowsL[tid] = nodelist[cr];
    } else {
      int g = mb * 128 + tid; if (g >= M) g = M - 1;
      rowsL[tid] = g;
    }
  }
  __syncthreads();

  f32x4 acc[4][4];
  #pragma unroll
  for (int i = 0; i < 4; ++i)
    #pragma unroll
    for (int j = 0; j < 4; ++j) acc[i][j] = (f32x4)0.0f;

  auto stage = [&](int buf, int kt){
    // A tile: 128 rows x 32 k = 512 x 16B chunks (1 per thread); 4 chunks/row, ^(row&3) swizzle
    {
      int ci = tid;
      int row = ci >> 2, p = ci & 3;
      int gch = p ^ (row & 3);                    // inverse-swizzled source
      const unsigned short* ga = A + (size_t)rowsL[row] * 256 + kt * 32 + gch * 8;
      __builtin_amdgcn_global_load_lds((const __attribute__((address_space(1))) void*)ga,
          (__attribute__((address_space(3))) void*)(As[buf] + (size_t)ci * 8), 16, 0, 0);
    }
    // B tile: 256 rows x 32 k = 1024 x 16B chunks (2 per thread)
    #pragma unroll
    for (int q = 0; q < 2; ++q){
      int ci = q * 512 + tid;
      int row = ci >> 2, p = ci & 3;
      int gch = p ^ (row & 3);
      const unsigned short* gb = Brel + (size_t)row * 256 + kt * 32 + gch * 8;
      __builtin_amdgcn_global_load_lds((const __attribute__((address_space(1))) void*)gb,
          (__attribute__((address_space(3))) void*)(Bs[buf] + (size_t)ci * 8), 16, 0, 0);
    }
  };

  stage(0, 0);
  __syncthreads();

  for (int kt = 0; kt < 8; ++kt){
    const int cur = kt & 1;
    if (kt < 7) stage(cur ^ 1, kt + 1);           // prefetch overlaps compute
    bf16x8 af[4], bg[4];
    #pragma unroll
    for (int mi = 0; mi < 4; ++mi){
      int row = wm + mi * 16 + lr;
      int pc = lg ^ (row & 3);
      af[mi] = *(const bf16x8*)&As[cur][row * 32 + pc * 8];
    }
    #pragma unroll
    for (int ni = 0; ni < 4; ++ni){
      int row = wn + ni * 16 + lr;
      int pc = lg ^ (row & 3);
      bg[ni] = *(const bf16x8*)&Bs[cur][row * 32 + pc * 8];
    }
    #pragma unroll
    for (int mi = 0; mi < 4; ++mi)
      #pragma unroll
      for (int ni = 0; ni < 4; ++ni)
        acc[mi][ni] = __builtin_amdgcn_mfma_f32_16x16x32_bf16(af[mi], bg[ni], acc[mi][ni], 0, 0, 0);
    __syncthreads();
  }

  // epilogue: C/D layout col=lane&15, row=(lane>>4)*4+reg
  if (MODE == 0){
    #pragma unroll
    for (int mi = 0; mi < 4; ++mi){
      #pragma unroll
      for (int j = 0; j < 4; ++j){
        int rowloc = wm + mi * 16 + lg * 4 + j;
        int cr = u0 + mb * 128 + rowloc;
        if (cr < u1){
          unsigned pk = pack4_fp8(acc[mi][0][j], acc[mi][1][j], acc[mi][2][j], acc[mi][3][j]);
          *(unsigned*)((unsigned char*)Cv + (size_t)cr * 256 + wn + lr * 4) = pk;
        }
      }
    }
  } else {
    #pragma unroll
    for (int mi = 0; mi < 4; ++mi){
      #pragma unroll
      for (int j = 0; j < 4; ++j){
        int rowm = mb * 128 + wm + mi * 16 + lg * 4 + j;
        if (rowm >= M) continue;
        #pragma unroll
        for (int ni = 0; ni < 4; ++ni){
          int col = wn + ni * 16 + lr;
          ((unsigned short*)Cv)[(size_t)rowm * H_ + col] = f2b(acc[mi][ni][j] + bias[col]);
        }
      }
    }
  }
}

// ================= fused softmax + aggregation: wave per node (packed fp8 xt) =================
__global__ void attn_agg_kernel(const unsigned char* __restrict__ xt8, const float* __restrict__ qdot,
                                const float* __restrict__ kdot, const int* __restrict__ ps2,
                                const int* __restrict__ es_src, const int* __restrict__ es_row,
                                float* __restrict__ a, unsigned short* __restrict__ hout, int n){
  int w = threadIdx.x >> 6, lane = threadIdx.x & 63;
  int node = blockIdx.x * 4 + w;
  if (node >= n) return;
  int kb = (node >> 5) * 1024 + (node & 31) * 32;
  // ---- phase A: softmax stats; lane r owns the node's (et=r) run; store raw exp
  int s = 0, e = 0;
  float qd = 0.f;
  if (lane < 32){
    s = ps2[kb + lane]; e = ps2[kb + lane + 1];
    qd = qdot[node * 32 + lane];
  }
  float m = -1e30f;
  for (int j = s; j < e; ++j){
    float z = qd + kdot[es_src[j] * 32 + lane];
    z = (z > 0.f) ? z : 0.2f * z;          // leaky_relu 0.2
    a[j] = z;
    m = fmaxf(m, z);
  }
  #pragma unroll
  for (int o = 32; o; o >>= 1) m = fmaxf(m, __shfl_xor(m, o));
  float sum = 0.f;
  for (int j = s; j < e; ++j){
    float ez = __expf(a[j] - m);
    a[j] = ez; sum += ez;
  }
  #pragma unroll
  for (int o = 32; o; o >>= 1) sum += __shfl_xor(sum, o);
  float inv = 1.0f / (sum + 1e-16f);
  // ---- phase B: aggregate; lane L's dword (bytes 4L..4L+3) = cols (4L&192)+k*16+(L&15)
  int s0 = ps2[kb], s1 = ps2[kb + 32];
  float a0 = 0.f, a1 = 0.f, a2 = 0.f, a3 = 0.f;
  int j = s0;
  for (; j + 2 <= s1; j += 2){
    int r0 = es_row[j], r1 = es_row[j+1];
    float w0 = a[j], w1 = a[j+1];
    unsigned v0 = ((const unsigned*)(xt8 + (size_t)r0 * 256))[lane];
    unsigned v1 = ((const unsigned*)(xt8 + (size_t)r1 * 256))[lane];
    f32x4 d0 = unpack4_fp8(v0), d1 = unpack4_fp8(v1);
    a0 += w0*d0[0] + w1*d1[0];
    a1 += w0*d0[1] + w1*d1[1];
    a2 += w0*d0[2] + w1*d1[2];
    a3 += w0*d0[3] + w1*d1[3];
  }
  for (; j < s1; ++j){
    float wv = a[j];
    unsigned v = ((const unsigned*)(xt8 + (size_t)es_row[j] * 256))[lane];
    f32x4 d = unpack4_fp8(v);
    a0 = fmaf(wv, d[0], a0);
    a1 = fmaf(wv, d[1], a1);
    a2 = fmaf(wv, d[2], a2);
    a3 = fmaf(wv, d[3], a3);
  }
  // hout: actual col for byte k = (lane&48)*4 + k*16 + (lane&15)
  int cb = ((lane & 48) << 2) + (lane & 15);
  unsigned short* hn = hout + (size_t)node * H_;
  hn[cb +  0] = f2b(fmaxf(a0 * inv, 0.f));
  hn[cb + 16] = f2b(fmaxf(a1 * inv, 0.f));
  hn[cb + 32] = f2b(fmaxf(a2 * inv, 0.f));
  hn[cb + 48] = f2b(fmaxf(a3 * inv, 0.f));
}

// ================= TransE scoring: 16-lane groups, bf16 h (L2-resident), 2-deep unroll =================
__global__ void score4_kernel(const unsigned short* __restrict__ hb, const float* __restrict__ relf,
                              const int* __restrict__ ps2, const int* __restrict__ es_src,
                              const int* __restrict__ es_et, const int* __restrict__ es_eid,
                              float* __restrict__ out, int n){
  int w = threadIdx.x >> 6, lane = threadIdx.x & 63;
  int node = blockIdx.x * 4 + w;
  if (node >= n) return;
  const int g = lane >> 4, cl = lane & 15;        // group (edge slot), column-lane
  int kb = (node >> 5) * 1024 + (node & 31) * 32;
  int s0 = ps2[kb], s1 = ps2[kb + 32];
  // dst row: lane owns cols cl*16..cl*16+15, decoded to fp32 regs
  float dv[16];
  {
    const ushort4* hd = (const ushort4*)(hb + (size_t)node * H_);
    #pragma unroll
    for (int q = 0; q < 4; ++q){
      ushort4 a = hd[cl * 4 + q];
      dv[4*q+0] = b2f(a.x); dv[4*q+1] = b2f(a.y);
      dv[4*q+2] = b2f(a.z); dv[4*q+3] = b2f(a.w);
    }
  }

  auto edge_sum = [&](int j)->float{
    int sc = es_src[j], r = es_et[j];
    const ushort4* hs = (const ushort4*)(hb + (size_t)sc * H_);
    const float4*  rv = (const float4*)(relf + (size_t)r * H_);
    float sum = 0.f;
    #pragma unroll
    for (int q = 0; q < 4; ++q){
      ushort4 a = hs[cl * 4 + q];
      float4  b = rv[cl * 4 + q];
      sum += fabsf(b2f(a.x) + b.x - dv[4*q+0]) + fabsf(b2f(a.y) + b.y - dv[4*q+1])
           + fabsf(b2f(a.z) + b.z - dv[4*q+2]) + fabsf(b2f(a.w) + b.w - dv[4*q+3]);
    }
    return sum;
  };

  int j = s0 + g;
  for (; j + 4 < s1; j += 8){                     // 2 edges per group in flight
    float sA = edge_sum(j), sB = edge_sum(j + 4);
    #pragma unroll
    for (int o = 8; o; o >>= 1){ sA += __shfl_xor(sA, o); sB += __shfl_xor(sB, o); }
    if (!cl){ out[es_eid[j]] = GAMMA_ - sA; out[es_eid[j + 4]] = GAMMA_ - sB; }
  }
  if (j < s1){
    float sA = edge_sum(j);
    #pragma unroll
    for (int o = 8; o; o >>= 1) sA += __shfl_xor(sA, o);
    if (!cl) out[es_eid[j]] = GAMMA_ - sA;
  }
}

extern "C" void kernel_launch(void* const* d_in, const int* in_sizes, int n_in,
                              void* d_out, int out_size, void* d_ws, size_t ws_size,
                              hipStream_t stream){
  const float* x         = (const float*)d_in[0];
  const int*   edge_idx  = (const int*)d_in[1];
  const int*   edge_type = (const int*)d_in[2];
  const float* W1        = (const float*)d_in[3];
  const float* q1        = (const float*)d_in[4];
  const float* k1        = (const float*)d_in[5];
  const float* W2        = (const float*)d_in[6];
  const float* q2        = (const float*)d_in[7];
  const float* k2        = (const float*)d_in[8];
  const float* lin_w     = (const float*)d_in[9];
  const float* lin_b     = (const float*)d_in[10];
  const float* rel_bert  = (const float*)d_in[11];
  const float* rel_lin_w = (const float*)d_in[12];
  const float* rel_lin_b = (const float*)d_in[13];
  float* score = (float*)d_out;

  const int Nn = in_sizes[0] / H_;   // 10000
  const int E  = in_sizes[1] / 2;    // 320000
  const int* src_a = edge_idx;
  const int* dst_a = edge_idx + E;
  const int NBLK   = (Nn + 31) / 32;              // 313 dst-bin blocks
  const int NBINS  = NBLK * 1024;
  const int NB2    = (R_ * Nn + 1023) / 1024;     // 313 flag blocks
  const int NBINS2 = NB2 * 1024;

  // workspace carve-up (256B aligned)
  char* ws = (char*)d_ws;
  size_t cur_off = 0;
  auto carve = [&](size_t bytes)->char*{
    char* p = ws + cur_off;
    cur_off += (bytes + 255) & ~(size_t)255;
    return p;
  };
  unsigned char*  xt8  = (unsigned char*)carve((size_t)Nn * R_ * H_);      // fp8, worst case
  unsigned short* xb   = (unsigned short*)carve((size_t)Nn * H_ * 2);
  unsigned short* h1   = (unsigned short*)carve((size_t)Nn * H_ * 2);
  unsigned short* h2   = (unsigned short*)carve((size_t)Nn * H_ * 2);
  unsigned short* outb = (unsigned short*)carve((size_t)Nn * H_ * 2);
  unsigned short* Wt1  = (unsigned short*)carve((size_t)R_ * 65536 * 2);
  unsigned short* Wt2  = (unsigned short*)carve((size_t)R_ * 65536 * 2);
  unsigned short* linT = (unsigned short*)carve(65536 * 2);
  float* relf  = (float*)carve((size_t)R_ * H_ * 4);
  float* wqkT1 = (float*)carve(64 * H_ * 4);
  float* wqkT2 = (float*)carve(64 * H_ * 4);
  float* qdot  = (float*)carve((size_t)Nn * R_ * 4);
  float* kdot  = (float*)carve((size_t)Nn * R_ * 4);
  int* cnt2    = (int*)carve((size_t)NBINS * 4);
  int* cur2    = (int*)carve((size_t)NBINS * 4);
  int* flagA   = (int*)carve((size_t)NBINS2 * 4);
  int* tot     = (int*)carve((size_t)NBLK * 4);
  int* tot2    = (int*)carve((size_t)NB2 * 4);
  int* baseA   = (int*)carve((size_t)(NBLK + 1) * 4);
  int* base2   = (int*)carve((size_t)(NB2 + 1) * 4);
  int* ps2     = (int*)carve((size_t)(NBINS + 1) * 4);
  int* ps3     = (int*)carve((size_t)(NBINS2 + 1) * 4);
  int* nodelist= (int*)carve((size_t)(R_ * Nn) * 4);
  int* es_src  = (int*)carve((size_t)E * 4);
  int* es_row  = (int*)carve((size_t)E * 4);
  int* es_et   = (int*)carve((size_t)E * 4);
  int* es_eid  = (int*)carve((size_t)E * 4);
  float* attn  = (float*)carve((size_t)E * 4);
  (void)ws_size; (void)n_in; (void)out_size;

  const int mt = (Nn + 127) / 128;         // 79
  const int nqd = (Nn + 3) / 4;            // 2500

  // prep block ranges (rel first — tail section overlaps the rest)
  const int n4 = Nn * H_ / 4;
  const int nb_rel = 256, nb0 = (n4 + 255) / 256, nb_tw = 2048, nb_lin = 64, nb_wqk = 2048;
  const int nb_hist = (E + 255) / 256;
  const int nprep = nb_rel + nb0 + 2 * nb_tw + nb_lin + 2 * nb_wqk + nb_hist;

  hipMemsetAsync(cnt2, 0, (size_t)NBINS * 4, stream);
  hipMemsetAsync(cur2, 0, (size_t)NBINS * 4, stream);
  hipMemsetAsync(flagA, 0, (size_t)NBINS2 * 4, stream);

  prep_kernel<<<nprep, 256, 0, stream>>>(
      x, xb, n4, W1, Wt1, W2, Wt2, lin_w, linT,
      q1, k1, wqkT1, q2, k2, wqkT2,
      rel_bert, rel_lin_w, rel_lin_b, relf,
      src_a, dst_a, edge_type, cnt2, flagA, E, Nn,
      nb_rel, nb0, nb_tw, nb_lin, nb_wqk, nb_hist);

  totred_kernel<<<NBLK + NB2, 256, 0, stream>>>(cnt2, tot, flagA, tot2, NBLK);
  scan_kernel<<<1, 1024, 0, stream>>>(tot, baseA, NBLK, tot2, base2, NB2);
  ps2scan_kernel<<<NBLK + NB2, 256, 0, stream>>>(cnt2, baseA, ps2, NBLK, flagA, base2, ps3, NB2);
  nodelist_kernel<<<(NBINS2 + 255) / 256, 256, 0, stream>>>(flagA, ps3, nodelist, R_ * Nn, Nn);
  scatter2_kernel<<<(E + 255) / 256, 256, 0, stream>>>(src_a, dst_a, edge_type, ps2, ps3, cur2,
                                                       es_src, es_row, es_et, es_eid, E, Nn);

  // ---- layer 1 ----
  gemm3_kernel<0><<<R_ * mt, 512, 0, stream>>>(xb, Wt1, xt8, nullptr, Nn, mt, nodelist, ps3, Nn);
  qdot_kernel<<<nqd, 256, 0, stream>>>(xb, wqkT1, qdot, kdot, Nn);
  attn_agg_kernel<<<nqd, 256, 0, stream>>>(xt8, qdot, kdot, ps2, es_src, es_row, attn, h1, Nn);

  // ---- layer 2 ----
  gemm3_kernel<0><<<R_ * mt, 512, 0, stream>>>(h1, Wt2, xt8, nullptr, Nn, mt, nodelist, ps3, Nn);
  qdot_kernel<<<nqd, 256, 0, stream>>>(h1, wqkT2, qdot, kdot, Nn);
  attn_agg_kernel<<<nqd, 256, 0, stream>>>(xt8, qdot, kdot, ps2, es_src, es_row, attn, h2, Nn);

  // ---- final linear + scoring ----
  gemm3_kernel<1><<<mt, 512, 0, stream>>>(h2, linT, outb, lin_b, Nn, mt, nullptr, nullptr, Nn);
  score4_kernel<<<nqd, 256, 0, stream>>>(outb, relf, ps2, es_src, es_et, es_eid, score, Nn);
}